// Round 2
// baseline (7561.550 us; speedup 1.0000x reference)
//
#include <hip/hip_runtime.h>
#include <math.h>

#define B 256
#define T 128
#define DD 300
#define H 512
#define FH 2048

typedef __attribute__((ext_vector_type(8))) short s8v;   // 8 bf16 (4 VGPR)
typedef __attribute__((ext_vector_type(4))) float f4v;   // MFMA acc

__device__ __forceinline__ float sigm(float x){ return 1.0f/(1.0f+expf(-x)); }

// round-to-nearest-even fp32 -> bf16 (inputs are finite)
__device__ __forceinline__ unsigned short f2bf(float x){
  unsigned u = __float_as_uint(x);
  return (unsigned short)((u + 0x7fffu + ((u>>16)&1u)) >> 16);
}
__device__ __forceinline__ float bf2f(unsigned short b){
  return __uint_as_float(((unsigned)b)<<16);
}

__device__ __forceinline__ f4v MFMA(s8v a, s8v b, f4v c){
  return __builtin_amdgcn_mfma_f32_16x16x32_bf16(a, b, c, 0, 0, 0);
}

#define GLD16(gp, lp) __builtin_amdgcn_global_load_lds( \
    (__attribute__((address_space(1))) void*)(gp), \
    (__attribute__((address_space(3))) void*)(lp), 16, 0, 0)

// ---------------------------------------------------------------------------
// Build recurrent-weight pack, fragment-major:
// WhPack[z][g][cg(32)][kk(48)][lane(64)][8] bf16
// value(lane,j): col = g*512 + cg*16 + (lane&15); k' = kk*32 + (lane>>4)*8 + j
// seg = k'>>9 in {0,1,2} -> {hi, lo, hi} of W[300 + (k'&511)][col]
// ---------------------------------------------------------------------------
__global__ __launch_bounds__(256)
void build_whpack(const float* __restrict__ Wp, const float* __restrict__ Whh,
                  short* __restrict__ out)
{
    int tid = blockIdx.x*256 + threadIdx.x;     // 2*4*32*48*64 = 786432
    int lane = tid & 63;
    int rest = tid >> 6;
    int kk = rest % 48; rest /= 48;
    int cg = rest & 31; rest >>= 5;
    int g  = rest & 3;
    int z  = rest >> 2;
    const float* W = z ? Whh : Wp;
    int col = g*512 + cg*16 + (lane & 15);
    int kbase = kk*32 + ((lane>>4)<<3);
    s8v v;
    #pragma unroll
    for (int j=0;j<8;++j){
        int kp = kbase + j;
        int seg = kp >> 9;
        int k = kp & 511;
        float w = W[(size_t)(DD + k)*FH + col];
        unsigned short hi = f2bf(w);
        unsigned short res = (seg==1) ? f2bf(w - bf2f(hi)) : hi;
        v[j] = (short)res;
    }
    *(s8v*)(out + (size_t)tid*8) = v;
}

// ---------------------------------------------------------------------------
// Build x-weight B^T split: WxT[z][n(2048)][k'(960)] bf16, linear rows.
// k' = seg*320 + kr, seg {0,1,2} -> {hi, lo, hi} of W[kr][n]; kr>=300 -> 0
// ---------------------------------------------------------------------------
__global__ __launch_bounds__(256)
void build_wxt(const float* __restrict__ Wp, const float* __restrict__ Whh,
               short* __restrict__ out)
{
    int tid = blockIdx.x*256 + threadIdx.x;     // 2*120*2048 = 491520
    int n = tid & 2047;
    int rest = tid >> 11;
    int k8 = rest % 120;
    int z = rest / 120;
    const float* W = z ? Whh : Wp;
    int seg = k8 / 40;
    int krb = (k8 % 40) * 8;
    s8v v;
    #pragma unroll
    for (int j=0;j<8;++j){
        int kr = krb + j;
        unsigned short res = 0;
        if (kr < DD){
            float w = W[(size_t)kr*FH + n];
            unsigned short hi = f2bf(w);
            res = (seg==1) ? f2bf(w - bf2f(hi)) : hi;
        }
        v[j] = (short)res;
    }
    *(s8v*)(out + ((size_t)(z*2048 + n)*120 + k8)*8) = v;
}

// ---------------------------------------------------------------------------
// X split convert for a super-chunk of CTX timesteps:
// Xsplit[z][rsc = tis*256 + b][960] bf16, k' = seg*320+kr,
// seg {0,1,2} -> {hi, hi, lo} of X[b][t0+tis][kr]; kr>=300 -> 0
// ---------------------------------------------------------------------------
__global__ __launch_bounds__(256)
void xsplit_convert(const float* __restrict__ Xp, const float* __restrict__ Xh,
                    short* __restrict__ out, int t0, int nrows)
{
    int tid = blockIdx.x*256 + threadIdx.x;     // 2*nrows*120
    int k8 = tid % 120;
    int rsc = (tid/120) % nrows;
    int z = tid / (120*nrows);
    const float* X = z ? Xh : Xp;
    int b = rsc & 255, tis = rsc >> 8;
    int seg = k8/40, krb = (k8%40)*8;
    const float* xr = X + ((size_t)b*T + (t0+tis))*DD;
    s8v v;
    #pragma unroll
    for (int j=0;j<8;++j){
        int kr = krb + j;
        unsigned short res = 0;
        if (kr < DD){
            float x = xr[kr];
            unsigned short hi = f2bf(x);
            res = (seg==2) ? f2bf(x - bf2f(hi)) : hi;
        }
        v[j] = (short)res;
    }
    *(s8v*)(out + ((size_t)(z*nrows + rsc)*120 + k8)*8) = v;
}

// ---------------------------------------------------------------------------
// Input projection GEMM (split-bf16 MFMA): XP[z][m(1024)][2048] =
//   Xsplit_rows @ WxT^T + bias.  m97-style 128x128 tile, BK=64, 4 waves.
// ---------------------------------------------------------------------------
__global__ __launch_bounds__(256)
void inproj_mfma(const short* __restrict__ Xs, const short* __restrict__ WxT,
                 const float* __restrict__ bp, const float* __restrict__ bh,
                 float* __restrict__ XP, int s, int zrows)
{
    const int z = blockIdx.z;
    const short* A  = Xs + ((size_t)z*zrows + (size_t)s*1024)*960;
    const short* Bm = WxT + (size_t)z*2048*960;
    const float* bias = z ? bh : bp;
    float* Out = XP + (size_t)z*1024*2048;

    const int m0 = blockIdx.x * 128;   // grid.x = 8
    const int n0 = blockIdx.y * 128;   // grid.y = 16
    const int t = threadIdx.x;
    const int lane = t & 63, w = t >> 6;
    const int wm = w & 1, wn = w >> 1;

    __shared__ short Al[128*64];
    __shared__ short Bl[128*64];

    f4v acc[4][4];
    #pragma unroll
    for (int i=0;i<4;++i)
        #pragma unroll
        for (int jj=0;jj<4;++jj) acc[i][jj] = (f4v){0.f,0.f,0.f,0.f};

    const int srow = t >> 3;        // 0..31
    const int scol = (t & 7) * 8;   // bf16 col offset within 64-k chunk

    for (int kt = 0; kt < 15; ++kt){
        const int kb = kt*64;
        #pragma unroll
        for (int r=0;r<4;++r)
            GLD16(A + (size_t)(m0 + r*32 + srow)*960 + kb + scol,
                  (char*)Al + r*4096 + t*16);
        #pragma unroll
        for (int r=0;r<4;++r)
            GLD16(Bm + (size_t)(n0 + r*32 + srow)*960 + kb + scol,
                  (char*)Bl + r*4096 + t*16);
        __syncthreads();           // drains vmcnt, publishes LDS
        #pragma unroll
        for (int kkh=0;kkh<2;++kkh){
            s8v af[4], bf[4];
            #pragma unroll
            for (int mf=0;mf<4;++mf)
                af[mf] = *(const s8v*)((const char*)Al +
                    (wm*64 + mf*16 + (lane&15))*128 + kkh*64 + (lane>>4)*16);
            #pragma unroll
            for (int nf=0;nf<4;++nf)
                bf[nf] = *(const s8v*)((const char*)Bl +
                    (wn*64 + nf*16 + (lane&15))*128 + kkh*64 + (lane>>4)*16);
            #pragma unroll
            for (int mf=0;mf<4;++mf)
                #pragma unroll
                for (int nf=0;nf<4;++nf)
                    acc[mf][nf] = MFMA(af[mf], bf[nf], acc[mf][nf]);
        }
        __syncthreads();           // protect LDS before next stage
    }

    const int rb = m0 + wm*64, cb = n0 + wn*64;
    #pragma unroll
    for (int nf=0;nf<4;++nf){
        const int c = cb + nf*16 + (lane&15);
        const float bv = bias[c];
        #pragma unroll
        for (int mf=0;mf<4;++mf){
            #pragma unroll
            for (int j=0;j<4;++j){
                const int r = rb + mf*16 + (lane>>4)*4 + j;
                Out[(size_t)r*2048 + c] = acc[mf][nf][j] + bv;
            }
        }
    }
}

// ---------------------------------------------------------------------------
// Fused LSTM step, LDS-free fragment-packed MFMA.
// z = XP_t + H' @ Wh'  (split-bf16, K'=1536); gates; writes Cst, Hlin, and
// next-step H' pack (Aout) with [hi|hi|lo] layout.
// Grid (16 c-tiles of 32, 4 m-tiles of 64, 2 LSTMs), 256 threads (4 waves).
// ---------------------------------------------------------------------------
__global__ __launch_bounds__(256)
void lstm_step_mfma(const short* __restrict__ Ain, short* __restrict__ Aout,
                    const short* __restrict__ Wh, const float* __restrict__ XP,
                    float* __restrict__ Cst, float* __restrict__ Hlin, int tsub)
{
    const int z = blockIdx.z;
    const int t = threadIdx.x, lane = t & 63, w = t >> 6;
    const int wm = w & 1, wn = w >> 1;
    const int cg  = blockIdx.x*2 + wn;        // 0..31 (16-wide col group)
    const int mgb = blockIdx.y*4 + wm*2;      // 0..14 step 2 (16-wide row group)
    const short* Az = Ain + (size_t)z*(16*48*512);
    const short* Wz = Wh  + (size_t)z*(4*32*48*512);

    f4v acc0[4], acc1[4];
    #pragma unroll
    for (int g=0;g<4;++g){ acc0[g]=(f4v){0.f,0.f,0.f,0.f}; acc1[g]=(f4v){0.f,0.f,0.f,0.f}; }

    #pragma unroll 4
    for (int kk=0; kk<48; ++kk){
        s8v a0 = *(const s8v*)(Az + ((size_t)((mgb  )*48 + kk)*64 + lane)*8);
        s8v a1 = *(const s8v*)(Az + ((size_t)((mgb+1)*48 + kk)*64 + lane)*8);
        #pragma unroll
        for (int g=0;g<4;++g){
            s8v bg = *(const s8v*)(Wz + ((size_t)((g*32 + cg)*48 + kk)*64 + lane)*8);
            acc0[g] = MFMA(a0, bg, acc0[g]);
            acc1[g] = MFMA(a1, bg, acc1[g]);
        }
    }

    const float* XPz = XP + ((size_t)z*1024 + (size_t)tsub*256)*2048;
    float* Cz = Cst  + (size_t)z*(256*512);
    float* Hz = Hlin + (size_t)z*(256*512);
    short* Ao = Aout + (size_t)z*(16*48*512);
    const int c = cg*16 + (lane&15);          // 0..511
    const int kk0 = c >> 5;
    const int lpb = ((c>>3)&3)*16;
    const int jp  = c & 7;

#define STEP_EPILOG(AV, MF)                                                    \
    {                                                                          \
        const int rB = (mgb+(MF))*16;                                          \
        _Pragma("unroll")                                                      \
        for (int j=0;j<4;++j){                                                 \
            const int row = rB + (lane>>4)*4 + j;                              \
            float zi = AV[0][j] + XPz[(size_t)row*2048 + c];                   \
            float zj = AV[1][j] + XPz[(size_t)row*2048 + 512 + c];             \
            float zf = AV[2][j] + XPz[(size_t)row*2048 + 1024 + c];            \
            float zo = AV[3][j] + XPz[(size_t)row*2048 + 1536 + c];            \
            const size_t ix = (size_t)row*512 + c;                             \
            float cn = Cz[ix]*sigm(zf + 1.0f) + sigm(zi)*tanhf(zj);            \
            float hn = tanhf(cn)*sigm(zo);                                     \
            Cz[ix] = cn; Hz[ix] = hn;                                          \
            unsigned short hi = f2bf(hn);                                      \
            unsigned short lo = f2bf(hn - bf2f(hi));                           \
            short* bp_ = Ao + ((size_t)((row>>4)*48 + kk0)*64 + lpb + (row&15))*8 + jp; \
            bp_[0] = (short)hi;                                                \
            bp_[(size_t)16*64*8] = (short)hi;                                  \
            bp_[(size_t)32*64*8] = (short)lo;                                  \
        }                                                                      \
    }
    STEP_EPILOG(acc0, 0)
    STEP_EPILOG(acc1, 1)
#undef STEP_EPILOG
}

// ---------------------------------------------------------------------------
// fp32 tail: C = tanh(A @ W + bias) (64x64 tiles) and final projection.
// ---------------------------------------------------------------------------
__global__ __launch_bounds__(256)
void gemm_tanh_kernel(const float* __restrict__ A, const float* __restrict__ W,
                      const float* __restrict__ bias, float* __restrict__ Cout,
                      int K, int N, int ldc, int coloff)
{
    const int n0 = blockIdx.x * 64;
    const int m0 = blockIdx.y * 64;
    const int t  = threadIdx.x;
    const int rc = t >> 4, cc = t & 15;

    __shared__ float As[16][68];
    __shared__ float Bs[16][64];

    float acc[4][4] = {};
    float areg[4], breg[4];

    const int ar = t >> 2;
    const int kq = (t & 3) * 4;
    const int kb = t >> 4;
    const int nb = (t & 15) * 4;

    {
        const float4 av = *(const float4*)(A + (size_t)(m0 + ar) * K + kq);
        areg[0]=av.x; areg[1]=av.y; areg[2]=av.z; areg[3]=av.w;
        const float4 bv = *(const float4*)(W + (size_t)kb * N + n0 + nb);
        breg[0]=bv.x; breg[1]=bv.y; breg[2]=bv.z; breg[3]=bv.w;
    }

    const int KT = K / 16;
    for (int kt = 0; kt < KT; ++kt){
        __syncthreads();
        As[kq+0][ar] = areg[0];
        As[kq+1][ar] = areg[1];
        As[kq+2][ar] = areg[2];
        As[kq+3][ar] = areg[3];
        *(float4*)&Bs[kb][nb] = make_float4(breg[0], breg[1], breg[2], breg[3]);
        __syncthreads();

        if (kt + 1 < KT){
            const int k0 = (kt + 1) * 16;
            const float4 av = *(const float4*)(A + (size_t)(m0 + ar) * K + k0 + kq);
            areg[0]=av.x; areg[1]=av.y; areg[2]=av.z; areg[3]=av.w;
            const float4 bv = *(const float4*)(W + (size_t)(k0 + kb) * N + n0 + nb);
            breg[0]=bv.x; breg[1]=bv.y; breg[2]=bv.z; breg[3]=bv.w;
        }

        #pragma unroll
        for (int k = 0; k < 16; ++k){
            const float4 a = *(const float4*)&As[k][4*rc];
            const float4 b = *(const float4*)&Bs[k][4*cc];
            acc[0][0] += a.x*b.x; acc[0][1] += a.x*b.y; acc[0][2] += a.x*b.z; acc[0][3] += a.x*b.w;
            acc[1][0] += a.y*b.x; acc[1][1] += a.y*b.y; acc[1][2] += a.y*b.z; acc[1][3] += a.y*b.w;
            acc[2][0] += a.z*b.x; acc[2][1] += a.z*b.y; acc[2][2] += a.z*b.z; acc[2][3] += a.z*b.w;
            acc[3][0] += a.w*b.x; acc[3][1] += a.w*b.y; acc[3][2] += a.w*b.z; acc[3][3] += a.w*b.w;
        }
    }

    const float4 bv = *(const float4*)(bias + n0 + 4*cc);
    #pragma unroll
    for (int ri = 0; ri < 4; ++ri){
        const int rg = m0 + 4*rc + ri;
        float4 res;
        res.x = tanhf(acc[ri][0] + bv.x);
        res.y = tanhf(acc[ri][1] + bv.y);
        res.z = tanhf(acc[ri][2] + bv.z);
        res.w = tanhf(acc[ri][3] + bv.w);
        *(float4*)&Cout[(size_t)rg * ldc + coloff + n0 + 4*cc] = res;
    }
}

__global__ __launch_bounds__(256)
void out_kernel(const float* __restrict__ A, const float* __restrict__ Wo,
                const float* __restrict__ bo, float* __restrict__ out)
{
    const int wave = threadIdx.x >> 6;
    const int lane = threadIdx.x & 63;
    const int r = blockIdx.x * 4 + wave;

    float a0 = 0.f, a1 = 0.f, a2 = 0.f;
    for (int k = lane; k < 1024; k += 64){
        const float a = A[(size_t)r * 1024 + k];
        a0 += a * Wo[k*3 + 0];
        a1 += a * Wo[k*3 + 1];
        a2 += a * Wo[k*3 + 2];
    }
    #pragma unroll
    for (int off = 32; off > 0; off >>= 1){
        a0 += __shfl_down(a0, off);
        a1 += __shfl_down(a1, off);
        a2 += __shfl_down(a2, off);
    }
    if (lane == 0){
        out[r*3 + 0] = a0 + bo[0];
        out[r*3 + 1] = a1 + bo[1];
        out[r*3 + 2] = a2 + bo[2];
    }
}

// ---------------------------------------------------------------------------
extern "C" void kernel_launch(void* const* d_in, const int* in_sizes, int n_in,
                              void* d_out, int out_size, void* d_ws, size_t ws_size,
                              hipStream_t stream)
{
    const float* premises   = (const float*)d_in[0];
    const float* hypotheses = (const float*)d_in[1];
    const float* W_lstm_p   = (const float*)d_in[2];
    const float* b_lstm_p   = (const float*)d_in[3];
    const float* W_lstm_h   = (const float*)d_in[4];
    const float* b_lstm_h   = (const float*)d_in[5];
    const float* W_red_p    = (const float*)d_in[6];
    const float* b_red_p    = (const float*)d_in[7];
    const float* W_red_h    = (const float*)d_in[8];
    const float* b_red_h    = (const float*)d_in[9];
    const float* W1 = (const float*)d_in[10];  const float* b1 = (const float*)d_in[11];
    const float* W2 = (const float*)d_in[12];  const float* b2 = (const float*)d_in[13];
    const float* W3 = (const float*)d_in[14];  const float* b3 = (const float*)d_in[15];
    const float* W_out = (const float*)d_in[16]; const float* b_out = (const float*)d_in[17];
    float* out = (float*)d_out;

    char* wsb = (char*)d_ws;
    size_t off = 0;
    auto alloc = [&](size_t bytes)->void*{
        void* p = wsb + off; off += (bytes + 255) & ~(size_t)255; return p;
    };
    short* WhPack = (short*)alloc(2ull*4*32*48*64*8*2);   // 12.58 MB
    short* WxT    = (short*)alloc(2ull*2048*960*2);       //  7.86 MB
    short* Apack0 = (short*)alloc(2ull*16*48*64*8*2);     //  1.57 MB
    short* Apack1 = (short*)alloc(2ull*16*48*64*8*2);     //  1.57 MB
    float* Cst    = (float*)alloc(2ull*256*512*4);        //  1.05 MB
    float* Hlin   = (float*)alloc(2ull*256*512*4);        //  1.05 MB
    float* XP     = (float*)alloc(2ull*1024*2048*4);      // 16.78 MB
    float* xbuf   = (float*)alloc(256ull*1024*4);
    float* t1b    = (float*)alloc(256ull*1024*4);
    float* t2b    = (float*)alloc(256ull*1024*4);
    float* t3b    = (float*)alloc(256ull*1024*4);

    int CTX = 16;                                          // super-chunk timesteps
    while (CTX > 4 && off + 2ull*CTX*256*960*2 > ws_size) CTX >>= 1;
    short* Xsplit = (short*)alloc(2ull*CTX*256*960*2);

    hipMemsetAsync(Apack0, 0, 2ull*16*48*64*8*2, stream);
    hipMemsetAsync(Cst,    0, 2ull*256*512*4, stream);

    build_whpack<<<3072, 256, 0, stream>>>(W_lstm_p, W_lstm_h, WhPack);
    build_wxt   <<<1920, 256, 0, stream>>>(W_lstm_p, W_lstm_h, WxT);

    short* Apk[2] = {Apack0, Apack1};
    for (int t0 = 0; t0 < T; t0 += CTX){
        xsplit_convert<<<240*CTX, 256, 0, stream>>>(premises, hypotheses,
                                                    Xsplit, t0, CTX*256);
        for (int s = 0; s < CTX/4; ++s){
            dim3 gi(8, 16, 2);
            inproj_mfma<<<gi, 256, 0, stream>>>(Xsplit, WxT, b_lstm_p, b_lstm_h,
                                                XP, s, CTX*256);
            for (int tsub = 0; tsub < 4; ++tsub){
                int tt = t0 + s*4 + tsub;
                dim3 gs(16, 4, 2);
                lstm_step_mfma<<<gs, 256, 0, stream>>>(Apk[tt&1], Apk[(tt+1)&1],
                                                       WhPack, XP, Cst, Hlin, tsub);
            }
        }
    }

    dim3 gr(8, 4);
    gemm_tanh_kernel<<<gr,256,0,stream>>>(Hlin,             W_red_p, b_red_p, xbuf, 512, 512, 1024, 0);
    gemm_tanh_kernel<<<gr,256,0,stream>>>(Hlin + 256*512,   W_red_h, b_red_h, xbuf, 512, 512, 1024, 512);
    dim3 gm(16, 4);
    gemm_tanh_kernel<<<gm,256,0,stream>>>(xbuf, W1, b1, t1b, 1024, 1024, 1024, 0);
    gemm_tanh_kernel<<<gm,256,0,stream>>>(t1b,  W2, b2, t2b, 1024, 1024, 1024, 0);
    gemm_tanh_kernel<<<gm,256,0,stream>>>(t2b,  W3, b3, t3b, 1024, 1024, 1024, 0);
    out_kernel<<<B/4, 256, 0, stream>>>(t3b, W_out, b_out, out);
}

// Round 4
// 3499.141 us; speedup vs baseline: 2.1610x; 2.1610x over previous
//
#include <hip/hip_runtime.h>
#include <math.h>

#define B 256
#define T 128
#define DD 300
#define H 512
#define FH 2048
#define CS 8                 // steps per persistent chunk launch
#define APK_BUF 524288       // shorts per A-pack buffer

typedef __attribute__((ext_vector_type(8))) short s8v;   // 8 bf16
typedef __attribute__((ext_vector_type(4))) float f4v;   // MFMA acc

__device__ __forceinline__ float sigm(float x){ return 1.0f/(1.0f+expf(-x)); }

__device__ __forceinline__ unsigned short f2bf(float x){
  unsigned u = __float_as_uint(x);
  return (unsigned short)((u + 0x7fffu + ((u>>16)&1u)) >> 16);
}
__device__ __forceinline__ float bf2f(unsigned short b){
  return __uint_as_float(((unsigned)b)<<16);
}

__device__ __forceinline__ f4v MFMA(s8v a, s8v b, f4v c){
  return __builtin_amdgcn_mfma_f32_16x16x32_bf16(a, b, c, 0, 0, 0);
}

#define GLD16(gp, lp) __builtin_amdgcn_global_load_lds( \
    (__attribute__((address_space(1))) void*)(gp), \
    (__attribute__((address_space(3))) void*)(lp), 16, 0, 0)

// ---------------------------------------------------------------------------
// Recurrent weight pack: [z][nt(32)][sel(2)][kk(16)][g(4)][lane(64)][8] bf16
// col = g*512 + nt*16 + (lane&15); k = kk*32 + (lane>>4)*8 + j (W row DD+k)
// sel0 = hi(W), sel1 = lo(W). Per (z,nt): 128KB contiguous (LDS stage image).
// ---------------------------------------------------------------------------
__global__ __launch_bounds__(256)
void build_whpack2(const float* __restrict__ Wp, const float* __restrict__ Whh,
                   short* __restrict__ out)
{
    int tid = blockIdx.x*256 + threadIdx.x;     // 524288 total
    int lane = tid & 63;
    int rest = tid >> 6;
    int g   = rest & 3;  rest >>= 2;
    int kk  = rest & 15; rest >>= 4;
    int sel = rest & 1;  rest >>= 1;
    int nt  = rest & 31; rest >>= 5;
    int z   = rest;
    const float* W = z ? Whh : Wp;
    int col = g*512 + nt*16 + (lane & 15);
    int kb  = kk*32 + ((lane >> 4) << 3);
    s8v v;
    #pragma unroll
    for (int j = 0; j < 8; ++j){
        float wv = W[(size_t)(DD + kb + j)*FH + col];
        unsigned short hi = f2bf(wv);
        v[j] = (short)(sel ? f2bf(wv - bf2f(hi)) : hi);
    }
    *(s8v*)(out + (size_t)tid*8) = v;
}

// ---------------------------------------------------------------------------
// x-weight B^T split: WxT[z][n(2048)][k'(960)] bf16; k' = seg*320+kr,
// seg {0,1,2} -> {hi, lo, hi} of W[kr][n]; kr>=300 -> 0
// ---------------------------------------------------------------------------
__global__ __launch_bounds__(256)
void build_wxt(const float* __restrict__ Wp, const float* __restrict__ Whh,
               short* __restrict__ out)
{
    int tid = blockIdx.x*256 + threadIdx.x;     // 491520
    int n = tid & 2047;
    int rest = tid >> 11;
    int k8 = rest % 120;
    int z = rest / 120;
    const float* W = z ? Whh : Wp;
    int seg = k8 / 40;
    int krb = (k8 % 40) * 8;
    s8v v;
    #pragma unroll
    for (int j = 0; j < 8; ++j){
        int kr = krb + j;
        unsigned short res = 0;
        if (kr < DD){
            float w = W[(size_t)kr*FH + n];
            unsigned short hi = f2bf(w);
            res = (seg==1) ? f2bf(w - bf2f(hi)) : hi;
        }
        v[j] = (short)res;
    }
    *(s8v*)(out + ((size_t)(z*2048 + n)*120 + k8)*8) = v;
}

// ---------------------------------------------------------------------------
// X split for one chunk: Xsplit[z][rsc = tis*256+b][960] bf16,
// seg {0,1,2} -> {hi, hi, lo} of X[b][t0+tis][kr]
// ---------------------------------------------------------------------------
__global__ __launch_bounds__(256)
void xsplit_convert(const float* __restrict__ Xp, const float* __restrict__ Xh,
                    short* __restrict__ out, int t0, int nrows)
{
    int tid = blockIdx.x*256 + threadIdx.x;     // 2*nrows*120
    int k8 = tid % 120;
    int rsc = (tid/120) % nrows;
    int z = tid / (120*nrows);
    const float* X = z ? Xh : Xp;
    int b = rsc & 255, tis = rsc >> 8;
    int seg = k8/40, krb = (k8%40)*8;
    const float* xr = X + ((size_t)b*T + (t0+tis))*DD;
    s8v v;
    #pragma unroll
    for (int j = 0; j < 8; ++j){
        int kr = krb + j;
        unsigned short res = 0;
        if (kr < DD){
            float x = xr[kr];
            unsigned short hi = f2bf(x);
            res = (seg==2) ? f2bf(x - bf2f(hi)) : hi;
        }
        v[j] = (short)res;
    }
    *(s8v*)(out + ((size_t)(z*nrows + rsc)*120 + k8)*8) = v;
}

// ---------------------------------------------------------------------------
// Input projection GEMM (split-bf16 MFMA), 128x128 tile, BK=64:
// XPb[z][row(zrows)][2048] = Xsplit @ WxT^T + bias
// ---------------------------------------------------------------------------
__global__ __launch_bounds__(256)
void inproj_mfma(const short* __restrict__ Xs, const short* __restrict__ WxT,
                 const float* __restrict__ bp, const float* __restrict__ bh,
                 float* __restrict__ XPb, int s, int zrows)
{
    const int z = blockIdx.z;
    const short* A  = Xs + ((size_t)z*zrows + (size_t)s*1024)*960;
    const short* Bm = WxT + (size_t)z*2048*960;
    const float* bias = z ? bh : bp;
    float* Out = XPb + (size_t)z*zrows*2048;

    const int m0 = blockIdx.x * 128;
    const int n0 = blockIdx.y * 128;
    const int t = threadIdx.x;
    const int lane = t & 63, w = t >> 6;
    const int wm = w & 1, wn = w >> 1;

    __shared__ short Al[128*64];
    __shared__ short Bl[128*64];

    f4v acc[4][4];
    #pragma unroll
    for (int i = 0; i < 4; ++i)
        #pragma unroll
        for (int jj = 0; jj < 4; ++jj) acc[i][jj] = (f4v){0.f,0.f,0.f,0.f};

    const int srow = t >> 3;
    const int scol = (t & 7) * 8;

    for (int kt = 0; kt < 15; ++kt){
        const int kb = kt*64;
        #pragma unroll
        for (int r = 0; r < 4; ++r)
            GLD16(A + (size_t)(m0 + r*32 + srow)*960 + kb + scol,
                  (char*)Al + r*4096 + t*16);
        #pragma unroll
        for (int r = 0; r < 4; ++r)
            GLD16(Bm + (size_t)(n0 + r*32 + srow)*960 + kb + scol,
                  (char*)Bl + r*4096 + t*16);
        __syncthreads();
        #pragma unroll
        for (int kkh = 0; kkh < 2; ++kkh){
            s8v af[4], bf[4];
            #pragma unroll
            for (int mf = 0; mf < 4; ++mf)
                af[mf] = *(const s8v*)((const char*)Al +
                    (wm*64 + mf*16 + (lane&15))*128 + kkh*64 + (lane>>4)*16);
            #pragma unroll
            for (int nf = 0; nf < 4; ++nf)
                bf[nf] = *(const s8v*)((const char*)Bl +
                    (wn*64 + nf*16 + (lane&15))*128 + kkh*64 + (lane>>4)*16);
            #pragma unroll
            for (int mf = 0; mf < 4; ++mf)
                #pragma unroll
                for (int nf = 0; nf < 4; ++nf)
                    acc[mf][nf] = MFMA(af[mf], bf[nf], acc[mf][nf]);
        }
        __syncthreads();
    }

    const int rb = m0 + wm*64, cb = n0 + wn*64;
    #pragma unroll
    for (int nf = 0; nf < 4; ++nf){
        const int c = cb + nf*16 + (lane&15);
        const float bv = bias[c];
        #pragma unroll
        for (int mf = 0; mf < 4; ++mf){
            #pragma unroll
            for (int j = 0; j < 4; ++j){
                const int r = rb + mf*16 + (lane>>4)*4 + j;
                Out[(size_t)r*2048 + c] = acc[mf][nf][j] + bv;
            }
        }
    }
}

// ---------------------------------------------------------------------------
// Persistent LSTM chunk kernel: 256 blocks (1/CU), 256 threads, CS steps.
// Block (z, mt, nt): rows mt*64..+64, hcols nt*16..+16, all 4 gates.
// Weights LDS-resident; C in registers; group-of-32 barrier per step.
// ---------------------------------------------------------------------------
#define LOADA(p0,p1,p2,p3, jv) { \
    const int sg_ = (jv) >> 4; const int kk_ = (jv) & 15; \
    const short* ap_ = rdp + (zmt2 + (sg_==2 ? 1 : 0))*32768 + kk_*2048 + lane*8; \
    p0 = *(const s8v*)(ap_);        p1 = *(const s8v*)(ap_ + 512); \
    p2 = *(const s8v*)(ap_ + 1024); p3 = *(const s8v*)(ap_ + 1536); }

#define DOJ(p0,p1,p2,p3, jv) { \
    const int ws_ = (((jv) >> 4) == 1) ? 1 : 0; const int kk_ = (jv) & 15; \
    const short* wp_ = Wlds + ws_*32768 + kk_*2048 + lane*8; \
    s8v w0_ = *(const s8v*)(wp_);        s8v w1_ = *(const s8v*)(wp_ + 512); \
    s8v w2_ = *(const s8v*)(wp_ + 1024); s8v w3_ = *(const s8v*)(wp_ + 1536); \
    acc[0][0]=MFMA(p0,w0_,acc[0][0]); acc[0][1]=MFMA(p0,w1_,acc[0][1]); \
    acc[0][2]=MFMA(p0,w2_,acc[0][2]); acc[0][3]=MFMA(p0,w3_,acc[0][3]); \
    acc[1][0]=MFMA(p1,w0_,acc[1][0]); acc[1][1]=MFMA(p1,w1_,acc[1][1]); \
    acc[1][2]=MFMA(p1,w2_,acc[1][2]); acc[1][3]=MFMA(p1,w3_,acc[1][3]); \
    acc[2][0]=MFMA(p2,w0_,acc[2][0]); acc[2][1]=MFMA(p2,w1_,acc[2][1]); \
    acc[2][2]=MFMA(p2,w2_,acc[2][2]); acc[2][3]=MFMA(p2,w3_,acc[2][3]); \
    acc[3][0]=MFMA(p3,w0_,acc[3][0]); acc[3][1]=MFMA(p3,w1_,acc[3][1]); \
    acc[3][2]=MFMA(p3,w2_,acc[3][2]); acc[3][3]=MFMA(p3,w3_,acc[3][3]); }

__global__ void __launch_bounds__(256, 1)
lstm_chunk(const short* __restrict__ Wpk, short* __restrict__ Apack,
           const float* __restrict__ XP, float* __restrict__ Cglob,
           float* __restrict__ Hlin, unsigned* __restrict__ bar, int cstep)
{
    __shared__ short Wlds[65536];            // 128 KB
    __shared__ float zone[4][4][64][4];      // 16 KB reduction scratch

    const int bx = blockIdx.x;
    const int z  = bx >> 7;
    const int mt = (bx >> 5) & 3;
    const int nt = bx & 31;
    const int gid = bx >> 5;                 // group = z*4+mt (32 blocks)
    const int t = threadIdx.x;
    const int lane = t & 63;
    const int w = t >> 6;

    // stage weight slice (128 KB linear) into LDS
    const short* wsrc = Wpk + (size_t)(z*32 + nt)*65536;
    #pragma unroll
    for (int it = 0; it < 32; ++it)
        GLD16((const char*)wsrc + it*4096 + t*16, (char*)Wlds + it*4096 + t*16);

    // epilogue ownership: thread -> (row r_loc, 4 contiguous hcols)
    const int r_loc = t >> 2;                // 0..63
    const int cq    = t & 3;
    const int rr    = mt*64 + r_loc;         // batch row
    const int c0    = nt*16 + cq*4;          // global hcol base
    const int mf_r  = r_loc >> 4;
    const int jj    = r_loc & 3;
    const int kkw   = c0 >> 5;               // = nt>>1
    // A-frag: (lane>>4)*8 + j must equal col&31 = (nt&1)*16 + cq*4 (+i)
    const int lanew = ((nt & 1)*2 + (cq >> 1))*16 + (r_loc & 15);
    const int jb    = (cq & 1)*4;

    float cre[4];
    { float4 cv = *(const float4*)&Cglob[((size_t)z*256 + rr)*512 + c0];
      cre[0]=cv.x; cre[1]=cv.y; cre[2]=cv.z; cre[3]=cv.w; }

    const size_t zmt2 = (size_t)((z*4 + mt)*2);
    const int wbase = w*12;

    __syncthreads();                         // W staged (drains vmcnt)

    for (int s = 0; s < CS; ++s){
        const int gstep = cstep + s;
        const short* rdp = Apack + ((gstep & 1) ? APK_BUF : 0);
        short*       wrp = Apack + ((gstep & 1) ? 0 : APK_BUF);

        // early XP load (consumed ~3000cy later in epilogue)
        float xp[4][4];
        #pragma unroll
        for (int g = 0; g < 4; ++g)
            *(float4*)&xp[g][0] =
                *(const float4*)&XP[((size_t)z*2048 + s*256 + rr)*2048 + g*512 + c0];

        f4v acc[4][4];
        #pragma unroll
        for (int i = 0; i < 4; ++i)
            #pragma unroll
            for (int g = 0; g < 4; ++g) acc[i][g] = (f4v){0.f,0.f,0.f,0.f};

        // K-split MFMA phase: wave w handles j = wbase..wbase+11 (of 48)
        s8v aA0,aA1,aA2,aA3, aB0,aB1,aB2,aB3, aC0,aC1,aC2,aC3,
            aD0,aD1,aD2,aD3, aE0,aE1,aE2,aE3, aF0,aF1,aF2,aF3;
        LOADA(aA0,aA1,aA2,aA3, wbase+0);
        LOADA(aB0,aB1,aB2,aB3, wbase+1);
        LOADA(aC0,aC1,aC2,aC3, wbase+2);
        LOADA(aD0,aD1,aD2,aD3, wbase+3);
        LOADA(aE0,aE1,aE2,aE3, wbase+4);
        LOADA(aF0,aF1,aF2,aF3, wbase+5);

        DOJ(aA0,aA1,aA2,aA3, wbase+0);  LOADA(aA0,aA1,aA2,aA3, wbase+6);
        DOJ(aB0,aB1,aB2,aB3, wbase+1);  LOADA(aB0,aB1,aB2,aB3, wbase+7);
        DOJ(aC0,aC1,aC2,aC3, wbase+2);  LOADA(aC0,aC1,aC2,aC3, wbase+8);
        DOJ(aD0,aD1,aD2,aD3, wbase+3);  LOADA(aD0,aD1,aD2,aD3, wbase+9);
        DOJ(aE0,aE1,aE2,aE3, wbase+4);  LOADA(aE0,aE1,aE2,aE3, wbase+10);
        DOJ(aF0,aF1,aF2,aF3, wbase+5);  LOADA(aF0,aF1,aF2,aF3, wbase+11);
        DOJ(aA0,aA1,aA2,aA3, wbase+6);
        DOJ(aB0,aB1,aB2,aB3, wbase+7);
        DOJ(aC0,aC1,aC2,aC3, wbase+8);
        DOJ(aD0,aD1,aD2,aD3, wbase+9);
        DOJ(aE0,aE1,aE2,aE3, wbase+10);
        DOJ(aF0,aF1,aF2,aF3, wbase+11);

        // cross-wave reduction (4 rounds, one per gate)
        float gv[4][4];
        #pragma unroll
        for (int g = 0; g < 4; ++g){
            __syncthreads();
            #pragma unroll
            for (int mf = 0; mf < 4; ++mf)
                *(f4v*)&zone[w][mf][lane][0] = acc[mf][g];
            __syncthreads();
            #pragma unroll
            for (int i = 0; i < 4; ++i){
                const int lr = ((r_loc >> 2) & 3)*16 + cq*4 + i;
                float sv = 0.f;
                #pragma unroll
                for (int ww = 0; ww < 4; ++ww)
                    sv += zone[ww][mf_r][lr][jj];
                gv[g][i] = sv;
            }
        }

        // gates + state update + next-step A-pack write
        unsigned short hi4[4], lo4[4];
        float hnv[4];
        #pragma unroll
        for (int i = 0; i < 4; ++i){
            const float zi = gv[0][i] + xp[0][i];
            const float zj = gv[1][i] + xp[1][i];
            const float zf = gv[2][i] + xp[2][i];
            const float zo = gv[3][i] + xp[3][i];
            const float cn = cre[i]*sigm(zf + 1.0f) + sigm(zi)*tanhf(zj);
            const float hn = tanhf(cn)*sigm(zo);
            cre[i] = cn;
            hnv[i] = hn;
            const unsigned short hb = f2bf(hn);
            hi4[i] = hb;
            lo4[i] = f2bf(hn - bf2f(hb));
        }
        {
            short* dhi = wrp + (zmt2+0)*32768 + kkw*2048 + mf_r*512 + lanew*8 + jb;
            short* dlo = wrp + (zmt2+1)*32768 + kkw*2048 + mf_r*512 + lanew*8 + jb;
            *(ushort4*)dhi = make_ushort4(hi4[0],hi4[1],hi4[2],hi4[3]);
            *(ushort4*)dlo = make_ushort4(lo4[0],lo4[1],lo4[2],lo4[3]);
        }
        if (gstep == T-1)
            *(float4*)&Hlin[((size_t)z*256 + rr)*512 + c0] =
                make_float4(hnv[0],hnv[1],hnv[2],hnv[3]);

        // group barrier (32 blocks share A-pack[z][mt])
        __syncthreads();
        if (t == 0){
            __hip_atomic_fetch_add(&bar[gid*16], 1u, __ATOMIC_RELEASE,
                                   __HIP_MEMORY_SCOPE_AGENT);
            const unsigned tgt = 32u*(unsigned)(gstep + 1);
            while (__hip_atomic_load(&bar[gid*16], __ATOMIC_RELAXED,
                                     __HIP_MEMORY_SCOPE_AGENT) < tgt)
                __builtin_amdgcn_s_sleep(2);
            (void)__hip_atomic_load(&bar[gid*16], __ATOMIC_ACQUIRE,
                                    __HIP_MEMORY_SCOPE_AGENT);
        }
        __syncthreads();
    }

    *(float4*)&Cglob[((size_t)z*256 + rr)*512 + c0] =
        make_float4(cre[0],cre[1],cre[2],cre[3]);
}

// ---------------------------------------------------------------------------
// fp32 tail
// ---------------------------------------------------------------------------
__global__ __launch_bounds__(256)
void gemm_tanh_kernel(const float* __restrict__ A, const float* __restrict__ W,
                      const float* __restrict__ bias, float* __restrict__ Cout,
                      int K, int N, int ldc, int coloff)
{
    const int n0 = blockIdx.x * 64;
    const int m0 = blockIdx.y * 64;
    const int t  = threadIdx.x;
    const int rc = t >> 4, cc = t & 15;

    __shared__ float As[16][68];
    __shared__ float Bs[16][64];

    float acc[4][4] = {};
    float areg[4], breg[4];

    const int ar = t >> 2;
    const int kq = (t & 3) * 4;
    const int kb = t >> 4;
    const int nb = (t & 15) * 4;

    {
        const float4 av = *(const float4*)(A + (size_t)(m0 + ar) * K + kq);
        areg[0]=av.x; areg[1]=av.y; areg[2]=av.z; areg[3]=av.w;
        const float4 bv = *(const float4*)(W + (size_t)kb * N + n0 + nb);
        breg[0]=bv.x; breg[1]=bv.y; breg[2]=bv.z; breg[3]=bv.w;
    }

    const int KT = K / 16;
    for (int kt = 0; kt < KT; ++kt){
        __syncthreads();
        As[kq+0][ar] = areg[0];
        As[kq+1][ar] = areg[1];
        As[kq+2][ar] = areg[2];
        As[kq+3][ar] = areg[3];
        *(float4*)&Bs[kb][nb] = make_float4(breg[0], breg[1], breg[2], breg[3]);
        __syncthreads();

        if (kt + 1 < KT){
            const int k0 = (kt + 1) * 16;
            const float4 av = *(const float4*)(A + (size_t)(m0 + ar) * K + k0 + kq);
            areg[0]=av.x; areg[1]=av.y; areg[2]=av.z; areg[3]=av.w;
            const float4 bv = *(const float4*)(W + (size_t)(k0 + kb) * N + n0 + nb);
            breg[0]=bv.x; breg[1]=bv.y; breg[2]=bv.z; breg[3]=bv.w;
        }

        #pragma unroll
        for (int k = 0; k < 16; ++k){
            const float4 a = *(const float4*)&As[k][4*rc];
            const float4 b = *(const float4*)&Bs[k][4*cc];
            acc[0][0] += a.x*b.x; acc[0][1] += a.x*b.y; acc[0][2] += a.x*b.z; acc[0][3] += a.x*b.w;
            acc[1][0] += a.y*b.x; acc[1][1] += a.y*b.y; acc[1][2] += a.y*b.z; acc[1][3] += a.y*b.w;
            acc[2][0] += a.z*b.x; acc[2][1] += a.z*b.y; acc[2][2] += a.z*b.z; acc[2][3] += a.z*b.w;
            acc[3][0] += a.w*b.x; acc[3][1] += a.w*b.y; acc[3][2] += a.w*b.z; acc[3][3] += a.w*b.w;
        }
    }

    const float4 bv = *(const float4*)(bias + n0 + 4*cc);
    #pragma unroll
    for (int ri = 0; ri < 4; ++ri){
        const int rg = m0 + 4*rc + ri;
        float4 res;
        res.x = tanhf(acc[ri][0] + bv.x);
        res.y = tanhf(acc[ri][1] + bv.y);
        res.z = tanhf(acc[ri][2] + bv.z);
        res.w = tanhf(acc[ri][3] + bv.w);
        *(float4*)&Cout[(size_t)rg * ldc + coloff + n0 + 4*cc] = res;
    }
}

__global__ __launch_bounds__(256)
void out_kernel(const float* __restrict__ A, const float* __restrict__ Wo,
                const float* __restrict__ bo, float* __restrict__ out)
{
    const int wave = threadIdx.x >> 6;
    const int lane = threadIdx.x & 63;
    const int r = blockIdx.x * 4 + wave;

    float a0 = 0.f, a1 = 0.f, a2 = 0.f;
    for (int k = lane; k < 1024; k += 64){
        const float a = A[(size_t)r * 1024 + k];
        a0 += a * Wo[k*3 + 0];
        a1 += a * Wo[k*3 + 1];
        a2 += a * Wo[k*3 + 2];
    }
    #pragma unroll
    for (int off = 32; off > 0; off >>= 1){
        a0 += __shfl_down(a0, off);
        a1 += __shfl_down(a1, off);
        a2 += __shfl_down(a2, off);
    }
    if (lane == 0){
        out[r*3 + 0] = a0 + bo[0];
        out[r*3 + 1] = a1 + bo[1];
        out[r*3 + 2] = a2 + bo[2];
    }
}

// ---------------------------------------------------------------------------
extern "C" void kernel_launch(void* const* d_in, const int* in_sizes, int n_in,
                              void* d_out, int out_size, void* d_ws, size_t ws_size,
                              hipStream_t stream)
{
    const float* premises   = (const float*)d_in[0];
    const float* hypotheses = (const float*)d_in[1];
    const float* W_lstm_p   = (const float*)d_in[2];
    const float* b_lstm_p   = (const float*)d_in[3];
    const float* W_lstm_h   = (const float*)d_in[4];
    const float* b_lstm_h   = (const float*)d_in[5];
    const float* W_red_p    = (const float*)d_in[6];
    const float* b_red_p    = (const float*)d_in[7];
    const float* W_red_h    = (const float*)d_in[8];
    const float* b_red_h    = (const float*)d_in[9];
    const float* W1 = (const float*)d_in[10];  const float* b1 = (const float*)d_in[11];
    const float* W2 = (const float*)d_in[12];  const float* b2 = (const float*)d_in[13];
    const float* W3 = (const float*)d_in[14];  const float* b3 = (const float*)d_in[15];
    const float* W_out = (const float*)d_in[16]; const float* b_out = (const float*)d_in[17];
    float* out = (float*)d_out;

    char* wsb = (char*)d_ws;
    size_t off = 0;
    auto alloc = [&](size_t bytes)->void*{
        void* p = wsb + off; off += (bytes + 255) & ~(size_t)255; return p;
    };
    short*    WhPack2 = (short*)alloc(4194304ull*2);      //  8.39 MB
    short*    WxT     = (short*)alloc(2ull*2048*960*2);   //  7.86 MB
    short*    Apack   = (short*)alloc(2ull*APK_BUF*2);    //  2.10 MB
    float*    Cglob   = (float*)alloc(2ull*256*512*4);    //  1.05 MB
    float*    Hlin    = (float*)alloc(2ull*256*512*4);    //  1.05 MB
    float*    XP      = (float*)alloc(2ull*2048*2048*4);  // 33.55 MB
    short*    Xsplit  = (short*)alloc(2ull*2048*960*2);   //  7.86 MB
    float*    xbuf    = (float*)alloc(256ull*1024*4);
    float*    t1b     = (float*)alloc(256ull*1024*4);
    float*    t2b     = (float*)alloc(256ull*1024*4);
    float*    t3b     = (float*)alloc(256ull*1024*4);
    unsigned* bar     = (unsigned*)alloc(4096);
    (void)ws_size;

    hipMemsetAsync(Apack, 0, 2ull*APK_BUF*2, stream);
    hipMemsetAsync(Cglob, 0, 2ull*256*512*4, stream);
    hipMemsetAsync(bar,   0, 4096, stream);

    build_whpack2<<<2048, 256, 0, stream>>>(W_lstm_p, W_lstm_h, WhPack2);
    build_wxt    <<<1920, 256, 0, stream>>>(W_lstm_p, W_lstm_h, WxT);

    for (int c = 0; c < T/CS; ++c){
        xsplit_convert<<<1920, 256, 0, stream>>>(premises, hypotheses,
                                                 Xsplit, c*CS, 2048);
        dim3 gi(16, 16, 2);
        inproj_mfma<<<gi, 256, 0, stream>>>(Xsplit, WxT, b_lstm_p, b_lstm_h,
                                            XP, 0, 2048);
        lstm_chunk<<<256, 256, 0, stream>>>(WhPack2, Apack, XP, Cglob, Hlin,
                                            bar, c*CS);
    }

    dim3 gr(8, 4);
    gemm_tanh_kernel<<<gr,256,0,stream>>>(Hlin,           W_red_p, b_red_p, xbuf, 512, 512, 1024, 0);
    gemm_tanh_kernel<<<gr,256,0,stream>>>(Hlin + 256*512, W_red_h, b_red_h, xbuf, 512, 512, 1024, 512);
    dim3 gm(16, 4);
    gemm_tanh_kernel<<<gm,256,0,stream>>>(xbuf, W1, b1, t1b, 1024, 1024, 1024, 0);
    gemm_tanh_kernel<<<gm,256,0,stream>>>(t1b,  W2, b2, t2b, 1024, 1024, 1024, 0);
    gemm_tanh_kernel<<<gm,256,0,stream>>>(t2b,  W3, b3, t3b, 1024, 1024, 1024, 0);
    out_kernel<<<B/4, 256, 0, stream>>>(t3b, W_out, b_out, out);
}

// Round 6
// 3240.049 us; speedup vs baseline: 2.3338x; 1.0800x over previous
//
#include <hip/hip_runtime.h>
#include <math.h>

#define B 256
#define T 128
#define DD 300
#define H 512
#define FH 2048
#define APK_BUF 524288       // shorts per A-pack buffer

typedef __attribute__((ext_vector_type(8))) short s8v;   // 8 bf16
typedef __attribute__((ext_vector_type(4))) float f4v;   // MFMA acc

__device__ __forceinline__ float sigm(float x){ return 1.0f/(1.0f+expf(-x)); }

__device__ __forceinline__ unsigned short f2bf(float x){
  unsigned u = __float_as_uint(x);
  return (unsigned short)((u + 0x7fffu + ((u>>16)&1u)) >> 16);
}
__device__ __forceinline__ float bf2f(unsigned short b){
  return __uint_as_float(((unsigned)b)<<16);
}

__device__ __forceinline__ f4v MFMA(s8v a, s8v b, f4v c){
  return __builtin_amdgcn_mfma_f32_16x16x32_bf16(a, b, c, 0, 0, 0);
}

#define GLD16(gp, lp) __builtin_amdgcn_global_load_lds( \
    (__attribute__((address_space(1))) void*)(gp), \
    (__attribute__((address_space(3))) void*)(lp), 16, 0, 0)

// ---------------------------------------------------------------------------
// Recurrent weight pack: [z][nt(32)][sel(2)][kk(16)][g(4)][lane(64)][8] bf16
// col = g*512 + nt*16 + (lane&15); k = kk*32 + (lane>>4)*8 + j (W row DD+k)
// sel0 = hi(W), sel1 = lo(W). Per (z,nt): 128KB contiguous (LDS stage image).
// ---------------------------------------------------------------------------
__global__ __launch_bounds__(256)
void build_whpack2(const float* __restrict__ Wp, const float* __restrict__ Whh,
                   short* __restrict__ out)
{
    int tid = blockIdx.x*256 + threadIdx.x;     // 524288 total
    int lane = tid & 63;
    int rest = tid >> 6;
    int g   = rest & 3;  rest >>= 2;
    int kk  = rest & 15; rest >>= 4;
    int sel = rest & 1;  rest >>= 1;
    int nt  = rest & 31; rest >>= 5;
    int z   = rest;
    const float* W = z ? Whh : Wp;
    int col = g*512 + nt*16 + (lane & 15);
    int kb  = kk*32 + ((lane >> 4) << 3);
    s8v v;
    #pragma unroll
    for (int j = 0; j < 8; ++j){
        float wv = W[(size_t)(DD + kb + j)*FH + col];
        unsigned short hi = f2bf(wv);
        v[j] = (short)(sel ? f2bf(wv - bf2f(hi)) : hi);
    }
    *(s8v*)(out + (size_t)tid*8) = v;
}

// ---------------------------------------------------------------------------
// x-weight B^T split: WxT[z][n(2048)][k'(960)] bf16; k' = seg*320+kr,
// seg {0,1,2} -> {hi, lo, hi} of W[kr][n]; kr>=300 -> 0
// ---------------------------------------------------------------------------
__global__ __launch_bounds__(256)
void build_wxt(const float* __restrict__ Wp, const float* __restrict__ Whh,
               short* __restrict__ out)
{
    int tid = blockIdx.x*256 + threadIdx.x;     // 491520
    int n = tid & 2047;
    int rest = tid >> 11;
    int k8 = rest % 120;
    int z = rest / 120;
    const float* W = z ? Whh : Wp;
    int seg = k8 / 40;
    int krb = (k8 % 40) * 8;
    s8v v;
    #pragma unroll
    for (int j = 0; j < 8; ++j){
        int kr = krb + j;
        unsigned short res = 0;
        if (kr < DD){
            float w = W[(size_t)kr*FH + n];
            unsigned short hi = f2bf(w);
            res = (seg==1) ? f2bf(w - bf2f(hi)) : hi;
        }
        v[j] = (short)res;
    }
    *(s8v*)(out + ((size_t)(z*2048 + n)*120 + k8)*8) = v;
}

// ---------------------------------------------------------------------------
// Input projection GEMM (split-bf16 MFMA), 128x128 tile, BK=64, with FUSED
// fp32->split-bf16 conversion of X on the A side (reg-staged), B via GLD16.
// XPb[z][row(zrows)][2048] = Xsplit(X) @ WxT^T + bias, row = tis*256 + b.
// A k' = seg*320+kr, seg {0,1,2} -> {hi, hi, lo} of X[b][t0+tis][kr].
// ---------------------------------------------------------------------------
__global__ __launch_bounds__(256)
void inproj_mfma(const float* __restrict__ Xp, const float* __restrict__ Xh,
                 const short* __restrict__ WxT,
                 const float* __restrict__ bp, const float* __restrict__ bh,
                 float* __restrict__ XPb, int t0, int zrows)
{
    const int z = blockIdx.z;
    const float* X  = z ? Xh : Xp;
    const short* Bm = WxT + (size_t)z*2048*960;
    const float* bias = z ? bh : bp;
    float* Out = XPb + (size_t)z*zrows*2048;

    const int m0 = blockIdx.x * 128;
    const int n0 = blockIdx.y * 128;
    const int t = threadIdx.x;
    const int lane = t & 63, w = t >> 6;
    const int wm = w & 1, wn = w >> 1;

    __shared__ short Al[128*64];
    __shared__ short Bl[128*64];

    f4v acc[4][4];
    #pragma unroll
    for (int i = 0; i < 4; ++i)
        #pragma unroll
        for (int jj = 0; jj < 4; ++jj) acc[i][jj] = (f4v){0.f,0.f,0.f,0.f};

    const int srow  = t >> 3;        // 0..31
    const int scol8 = (t & 7) * 8;   // k'-element offset within 64-k chunk

    float xreg[4][8];

    auto loadx = [&](int kb){
        const int kp  = kb + scol8;                       // 0..952, mult of 8
        const int seg = (kp >= 640) ? 2 : ((kp >= 320) ? 1 : 0);
        const int kr  = kp - seg*320;                     // 0..312
        #pragma unroll
        for (int r = 0; r < 4; ++r){
            const int rg = m0 + r*32 + srow;
            const float* xr = X + ((size_t)(rg & 255)*T + (t0 + (rg >> 8)))*DD + kr;
            if (kr + 7 < DD){
                float4 a = *(const float4*)xr;
                float4 b = *(const float4*)(xr + 4);
                xreg[r][0]=a.x; xreg[r][1]=a.y; xreg[r][2]=a.z; xreg[r][3]=a.w;
                xreg[r][4]=b.x; xreg[r][5]=b.y; xreg[r][6]=b.z; xreg[r][7]=b.w;
            } else {
                #pragma unroll
                for (int j = 0; j < 8; ++j)
                    xreg[r][j] = (kr + j < DD) ? xr[j] : 0.0f;
            }
        }
    };
    auto pubx = [&](int kb){
        const int kp  = kb + scol8;
        const bool lo = (kp >= 640);
        #pragma unroll
        for (int r = 0; r < 4; ++r){
            s8v o;
            #pragma unroll
            for (int j = 0; j < 8; ++j){
                const float v = xreg[r][j];
                const unsigned short hb = f2bf(v);
                o[j] = (short)(lo ? f2bf(v - bf2f(hb)) : hb);
            }
            *(s8v*)((char*)Al + r*4096 + t*16) = o;
        }
    };

    loadx(0);

    for (int kt = 0; kt < 15; ++kt){
        const int kb = kt*64;
        __syncthreads();                 // LDS free (prev MFMA done)
        pubx(kb);                        // A: convert + ds_write_b128
        #pragma unroll
        for (int r = 0; r < 4; ++r)      // B: async global->LDS
            GLD16(Bm + (size_t)(n0 + r*32 + srow)*960 + kb + scol8,
                  (char*)Bl + r*4096 + t*16);
        __syncthreads();                 // drains vmcnt + lgkm, publishes A,B
        if (kt + 1 < 15) loadx(kb + 64); // prefetch next X regs under MFMA
        #pragma unroll
        for (int kkh = 0; kkh < 2; ++kkh){
            s8v af[4], bf[4];
            #pragma unroll
            for (int mf = 0; mf < 4; ++mf)
                af[mf] = *(const s8v*)((const char*)Al +
                    (wm*64 + mf*16 + (lane&15))*128 + kkh*64 + (lane>>4)*16);
            #pragma unroll
            for (int nf = 0; nf < 4; ++nf)
                bf[nf] = *(const s8v*)((const char*)Bl +
                    (wn*64 + nf*16 + (lane&15))*128 + kkh*64 + (lane>>4)*16);
            #pragma unroll
            for (int mf = 0; mf < 4; ++mf)
                #pragma unroll
                for (int nf = 0; nf < 4; ++nf)
                    acc[mf][nf] = MFMA(af[mf], bf[nf], acc[mf][nf]);
        }
    }

    const int rb = m0 + wm*64, cb = n0 + wn*64;
    #pragma unroll
    for (int nf = 0; nf < 4; ++nf){
        const int c = cb + nf*16 + (lane&15);
        const float bv = bias[c];
        #pragma unroll
        for (int mf = 0; mf < 4; ++mf){
            #pragma unroll
            for (int j = 0; j < 4; ++j){
                const int r = rb + mf*16 + (lane>>4)*4 + j;
                Out[(size_t)r*2048 + c] = acc[mf][nf][j] + bv;
            }
        }
    }
}

// ---------------------------------------------------------------------------
// Persistent LSTM chunk kernel: 256 blocks (1/CU), 256 threads, nsteps steps.
// gid = bx&7 -> all 32 blocks of a group land on one XCD (round-robin
// heuristic; correctness guaranteed by agent-scope fences regardless).
// Block (z, mt, nt): rows mt*64..+64, hcols nt*16..+16, all 4 gates.
// Weights LDS-resident; C in registers; K split across 4 waves; b128
// cross-wave reduction; XP folded in post-reduction.
// ---------------------------------------------------------------------------
#define LOADA(p0,p1,p2,p3, jv) { \
    const int sg_ = (jv) >> 4; const int kk_ = (jv) & 15; \
    const short* ap_ = rdp + (zmt2 + (sg_==2 ? 1 : 0))*32768 + kk_*2048 + lane*8; \
    p0 = *(const s8v*)(ap_);        p1 = *(const s8v*)(ap_ + 512); \
    p2 = *(const s8v*)(ap_ + 1024); p3 = *(const s8v*)(ap_ + 1536); }

#define DOJ(p0,p1,p2,p3, jv) { \
    const int ws_ = (((jv) >> 4) == 1) ? 1 : 0; const int kk_ = (jv) & 15; \
    const short* wp_ = Wlds + ws_*32768 + kk_*2048 + lane*8; \
    s8v w0_ = *(const s8v*)(wp_);        s8v w1_ = *(const s8v*)(wp_ + 512); \
    s8v w2_ = *(const s8v*)(wp_ + 1024); s8v w3_ = *(const s8v*)(wp_ + 1536); \
    acc[0][0]=MFMA(p0,w0_,acc[0][0]); acc[0][1]=MFMA(p0,w1_,acc[0][1]); \
    acc[0][2]=MFMA(p0,w2_,acc[0][2]); acc[0][3]=MFMA(p0,w3_,acc[0][3]); \
    acc[1][0]=MFMA(p1,w0_,acc[1][0]); acc[1][1]=MFMA(p1,w1_,acc[1][1]); \
    acc[1][2]=MFMA(p1,w2_,acc[1][2]); acc[1][3]=MFMA(p1,w3_,acc[1][3]); \
    acc[2][0]=MFMA(p2,w0_,acc[2][0]); acc[2][1]=MFMA(p2,w1_,acc[2][1]); \
    acc[2][2]=MFMA(p2,w2_,acc[2][2]); acc[2][3]=MFMA(p2,w3_,acc[2][3]); \
    acc[3][0]=MFMA(p3,w0_,acc[3][0]); acc[3][1]=MFMA(p3,w1_,acc[3][1]); \
    acc[3][2]=MFMA(p3,w2_,acc[3][2]); acc[3][3]=MFMA(p3,w3_,acc[3][3]); }

__global__ void __launch_bounds__(256, 1)
lstm_chunk(const short* __restrict__ Wpk, short* __restrict__ Apack,
           const float* __restrict__ XP, float* __restrict__ Cglob,
           float* __restrict__ Hlin, unsigned* __restrict__ bar,
           int cstep, int nsteps, int zrows, int bbase)
{
    __shared__ short Wlds[65536];            // 128 KB
    __shared__ f4v zone[4][4][64];           // 16 KB: [ww][mf][lane]

    const int bx = blockIdx.x;
    const int gid = bx & 7;                  // group -> XCD (round-robin)
    const int nt  = bx >> 3;                 // 0..31
    const int z   = gid >> 2;
    const int mt  = gid & 3;
    const int t = threadIdx.x;
    const int lane = t & 63;
    const int w = t >> 6;

    // stage weight slice (128 KB linear) into LDS
    const short* wsrc = Wpk + (size_t)(z*32 + nt)*65536;
    #pragma unroll
    for (int it = 0; it < 32; ++it)
        GLD16((const char*)wsrc + it*4096 + t*16, (char*)Wlds + it*4096 + t*16);

    // post-reduction ownership: thread (w,lane) owns rows of mf=w block
    const int col   = nt*16 + (lane & 15);            // global h col
    const int rbase = mt*64 + w*16 + ((lane>>4)<<2);  // +j -> global batch row
    // A-pack write constants (round-trip verified vs LOADA):
    const int kkw    = nt >> 1;
    const int lanew0 = ((nt & 1)*2 + ((lane & 15) >> 3))*16 + ((lane>>4)<<2);
    const int jw     = lane & 7;

    float cre[4];
    #pragma unroll
    for (int j = 0; j < 4; ++j)
        cre[j] = Cglob[((size_t)z*256 + rbase + j)*512 + col];

    const size_t zmt2 = (size_t)((z*4 + mt)*2);
    const int wbase = w*12;

    __syncthreads();                         // W staged (drains vmcnt)

    for (int s = 0; s < nsteps; ++s){
        const int gstep = cstep + s;
        const short* rdp = Apack + ((gstep & 1) ? APK_BUF : 0);
        short*       wrp = Apack + ((gstep & 1) ? 0 : APK_BUF);

        // XP for this thread's (mf=w, lane) rows, all 4 gates (early issue)
        const float* XPz = XP + ((size_t)z*zrows + (size_t)s*256 + mt*64)*2048;
        f4v xpe[4];
        #pragma unroll
        for (int g = 0; g < 4; ++g)
            #pragma unroll
            for (int j = 0; j < 4; ++j)
                xpe[g][j] = XPz[(size_t)(w*16 + ((lane>>4)<<2) + j)*2048 + g*512 + col];

        f4v acc[4][4];
        #pragma unroll
        for (int i = 0; i < 4; ++i)
            #pragma unroll
            for (int g = 0; g < 4; ++g) acc[i][g] = (f4v){0.f,0.f,0.f,0.f};

        // K-split MFMA phase: wave w handles j = wbase..wbase+11 (of 48)
        s8v aA0,aA1,aA2,aA3, aB0,aB1,aB2,aB3, aC0,aC1,aC2,aC3,
            aD0,aD1,aD2,aD3, aE0,aE1,aE2,aE3, aF0,aF1,aF2,aF3;
        LOADA(aA0,aA1,aA2,aA3, wbase+0);
        LOADA(aB0,aB1,aB2,aB3, wbase+1);
        LOADA(aC0,aC1,aC2,aC3, wbase+2);
        LOADA(aD0,aD1,aD2,aD3, wbase+3);
        LOADA(aE0,aE1,aE2,aE3, wbase+4);
        LOADA(aF0,aF1,aF2,aF3, wbase+5);

        DOJ(aA0,aA1,aA2,aA3, wbase+0);  LOADA(aA0,aA1,aA2,aA3, wbase+6);
        DOJ(aB0,aB1,aB2,aB3, wbase+1);  LOADA(aB0,aB1,aB2,aB3, wbase+7);
        DOJ(aC0,aC1,aC2,aC3, wbase+2);  LOADA(aC0,aC1,aC2,aC3, wbase+8);
        DOJ(aD0,aD1,aD2,aD3, wbase+3);  LOADA(aD0,aD1,aD2,aD3, wbase+9);
        DOJ(aE0,aE1,aE2,aE3, wbase+4);  LOADA(aE0,aE1,aE2,aE3, wbase+10);
        DOJ(aF0,aF1,aF2,aF3, wbase+5);  LOADA(aF0,aF1,aF2,aF3, wbase+11);
        DOJ(aA0,aA1,aA2,aA3, wbase+6);
        DOJ(aB0,aB1,aB2,aB3, wbase+7);
        DOJ(aC0,aC1,aC2,aC3, wbase+8);
        DOJ(aD0,aD1,aD2,aD3, wbase+9);
        DOJ(aE0,aE1,aE2,aE3, wbase+10);
        DOJ(aF0,aF1,aF2,aF3, wbase+11);

        // cross-wave reduction: 4 rounds, all-b128
        f4v gv[4];
        #pragma unroll
        for (int g = 0; g < 4; ++g){
            __syncthreads();
            #pragma unroll
            for (int mf = 0; mf < 4; ++mf)
                zone[w][mf][lane] = acc[mf][g];
            __syncthreads();
            gv[g] = zone[0][w][lane] + zone[1][w][lane]
                  + zone[2][w][lane] + zone[3][w][lane];
        }

        // gates + state update
        unsigned short hi4[4], lo4[4];
        #pragma unroll
        for (int j = 0; j < 4; ++j){
            const float zi = gv[0][j] + xpe[0][j];
            const float zj = gv[1][j] + xpe[1][j];
            const float zf = gv[2][j] + xpe[2][j];
            const float zo = gv[3][j] + xpe[3][j];
            const float cn = cre[j]*sigm(zf + 1.0f) + sigm(zi)*tanhf(zj);
            const float hn = tanhf(cn)*sigm(zo);
            cre[j] = cn;
            const unsigned short hb = f2bf(hn);
            hi4[j] = hb;
            lo4[j] = f2bf(hn - bf2f(hb));
            if (gstep == T-1)
                Hlin[((size_t)z*256 + rbase + j)*512 + col] = hn;
        }
        // next-step A-pack write (8 scalar shorts)
        {
            short* d0 = wrp + (zmt2+0)*32768 + kkw*2048 + w*512 + jw;
            short* d1 = wrp + (zmt2+1)*32768 + kkw*2048 + w*512 + jw;
            #pragma unroll
            for (int j = 0; j < 4; ++j){
                d0[(lanew0 + j)*8] = (short)hi4[j];
                d1[(lanew0 + j)*8] = (short)lo4[j];
            }
        }

        // group barrier (skip on last step of dispatch; kernel boundary syncs)
        if (s + 1 < nsteps){
            __syncthreads();
            if (t == 0){
                __hip_atomic_fetch_add(&bar[gid*16], 1u, __ATOMIC_RELEASE,
                                       __HIP_MEMORY_SCOPE_AGENT);
                const unsigned tgt = 32u*(unsigned)(bbase + s + 1);
                while (__hip_atomic_load(&bar[gid*16], __ATOMIC_RELAXED,
                                         __HIP_MEMORY_SCOPE_AGENT) < tgt)
                    __builtin_amdgcn_s_sleep(2);
                (void)__hip_atomic_load(&bar[gid*16], __ATOMIC_ACQUIRE,
                                        __HIP_MEMORY_SCOPE_AGENT);
            }
            __syncthreads();
        }
    }

    #pragma unroll
    for (int j = 0; j < 4; ++j)
        Cglob[((size_t)z*256 + rbase + j)*512 + col] = cre[j];
}

// ---------------------------------------------------------------------------
// fp32 tail
// ---------------------------------------------------------------------------
__global__ __launch_bounds__(256)
void gemm_tanh_kernel(const float* __restrict__ A, const float* __restrict__ W,
                      const float* __restrict__ bias, float* __restrict__ Cout,
                      int K, int N, int ldc, int coloff)
{
    const int n0 = blockIdx.x * 64;
    const int m0 = blockIdx.y * 64;
    const int t  = threadIdx.x;
    const int rc = t >> 4, cc = t & 15;

    __shared__ float As[16][68];
    __shared__ float Bs[16][64];

    float acc[4][4] = {};
    float areg[4], breg[4];

    const int ar = t >> 2;
    const int kq = (t & 3) * 4;
    const int kb = t >> 4;
    const int nb = (t & 15) * 4;

    {
        const float4 av = *(const float4*)(A + (size_t)(m0 + ar) * K + kq);
        areg[0]=av.x; areg[1]=av.y; areg[2]=av.z; areg[3]=av.w;
        const float4 bv = *(const float4*)(W + (size_t)kb * N + n0 + nb);
        breg[0]=bv.x; breg[1]=bv.y; breg[2]=bv.z; breg[3]=bv.w;
    }

    const int KT = K / 16;
    for (int kt = 0; kt < KT; ++kt){
        __syncthreads();
        As[kq+0][ar] = areg[0];
        As[kq+1][ar] = areg[1];
        As[kq+2][ar] = areg[2];
        As[kq+3][ar] = areg[3];
        *(float4*)&Bs[kb][nb] = make_float4(breg[0], breg[1], breg[2], breg[3]);
        __syncthreads();

        if (kt + 1 < KT){
            const int k0 = (kt + 1) * 16;
            const float4 av = *(const float4*)(A + (size_t)(m0 + ar) * K + k0 + kq);
            areg[0]=av.x; areg[1]=av.y; areg[2]=av.z; areg[3]=av.w;
            const float4 bv = *(const float4*)(W + (size_t)(k0 + kb) * N + n0 + nb);
            breg[0]=bv.x; breg[1]=bv.y; breg[2]=bv.z; breg[3]=bv.w;
        }

        #pragma unroll
        for (int k = 0; k < 16; ++k){
            const float4 a = *(const float4*)&As[k][4*rc];
            const float4 b = *(const float4*)&Bs[k][4*cc];
            acc[0][0] += a.x*b.x; acc[0][1] += a.x*b.y; acc[0][2] += a.x*b.z; acc[0][3] += a.x*b.w;
            acc[1][0] += a.y*b.x; acc[1][1] += a.y*b.y; acc[1][2] += a.y*b.z; acc[1][3] += a.y*b.w;
            acc[2][0] += a.z*b.x; acc[2][1] += a.z*b.y; acc[2][2] += a.z*b.z; acc[2][3] += a.z*b.w;
            acc[3][0] += a.w*b.x; acc[3][1] += a.w*b.y; acc[3][2] += a.w*b.z; acc[3][3] += a.w*b.w;
        }
    }

    const float4 bv = *(const float4*)(bias + n0 + 4*cc);
    #pragma unroll
    for (int ri = 0; ri < 4; ++ri){
        const int rg = m0 + 4*rc + ri;
        float4 res;
        res.x = tanhf(acc[ri][0] + bv.x);
        res.y = tanhf(acc[ri][1] + bv.y);
        res.z = tanhf(acc[ri][2] + bv.z);
        res.w = tanhf(acc[ri][3] + bv.w);
        *(float4*)&Cout[(size_t)rg * ldc + coloff + n0 + 4*cc] = res;
    }
}

__global__ __launch_bounds__(256)
void out_kernel(const float* __restrict__ A, const float* __restrict__ Wo,
                const float* __restrict__ bo, float* __restrict__ out)
{
    const int wave = threadIdx.x >> 6;
    const int lane = threadIdx.x & 63;
    const int r = blockIdx.x * 4 + wave;

    float a0 = 0.f, a1 = 0.f, a2 = 0.f;
    for (int k = lane; k < 1024; k += 64){
        const float a = A[(size_t)r * 1024 + k];
        a0 += a * Wo[k*3 + 0];
        a1 += a * Wo[k*3 + 1];
        a2 += a * Wo[k*3 + 2];
    }
    #pragma unroll
    for (int off = 32; off > 0; off >>= 1){
        a0 += __shfl_down(a0, off);
        a1 += __shfl_down(a1, off);
        a2 += __shfl_down(a2, off);
    }
    if (lane == 0){
        out[r*3 + 0] = a0 + bo[0];
        out[r*3 + 1] = a1 + bo[1];
        out[r*3 + 2] = a2 + bo[2];
    }
}

// ---------------------------------------------------------------------------
extern "C" void kernel_launch(void* const* d_in, const int* in_sizes, int n_in,
                              void* d_out, int out_size, void* d_ws, size_t ws_size,
                              hipStream_t stream)
{
    const float* premises   = (const float*)d_in[0];
    const float* hypotheses = (const float*)d_in[1];
    const float* W_lstm_p   = (const float*)d_in[2];
    const float* b_lstm_p   = (const float*)d_in[3];
    const float* W_lstm_h   = (const float*)d_in[4];
    const float* b_lstm_h   = (const float*)d_in[5];
    const float* W_red_p    = (const float*)d_in[6];
    const float* b_red_p    = (const float*)d_in[7];
    const float* W_red_h    = (const float*)d_in[8];
    const float* b_red_h    = (const float*)d_in[9];
    const float* W1 = (const float*)d_in[10];  const float* b1 = (const float*)d_in[11];
    const float* W2 = (const float*)d_in[12];  const float* b2 = (const float*)d_in[13];
    const float* W3 = (const float*)d_in[14];  const float* b3 = (const float*)d_in[15];
    const float* W_out = (const float*)d_in[16]; const float* b_out = (const float*)d_in[17];
    float* out = (float*)d_out;

    // need(CS) = fixed ~24.7 MB + XP (CS*4.20 MB)
    const int CS = (ws_size >= 92000000ull) ? 16 : 8;
    const int zrows = CS * 256;

    char* wsb = (char*)d_ws;
    size_t off = 0;
    auto alloc = [&](size_t bytes)->void*{
        void* p = wsb + off; off += (bytes + 255) & ~(size_t)255; return p;
    };
    short*    WhPack2 = (short*)alloc(4194304ull*2);            //  8.39 MB
    short*    WxT     = (short*)alloc(2ull*2048*960*2);         //  7.86 MB
    short*    Apack   = (short*)alloc(2ull*APK_BUF*2);          //  2.10 MB
    float*    Cglob   = (float*)alloc(2ull*256*512*4);          //  1.05 MB
    float*    Hlin    = (float*)alloc(2ull*256*512*4);          //  1.05 MB
    float*    XP      = (float*)alloc(2ull*zrows*2048*4);       // 33.5/67.1 MB
    float*    xbuf    = (float*)alloc(256ull*1024*4);
    float*    t1b     = (float*)alloc(256ull*1024*4);
    float*    t2b     = (float*)alloc(256ull*1024*4);
    float*    t3b     = (float*)alloc(256ull*1024*4);
    unsigned* bar     = (unsigned*)alloc(4096);

    hipMemsetAsync(Apack, 0, 2ull*APK_BUF*2, stream);
    hipMemsetAsync(Cglob, 0, 2ull*256*512*4, stream);
    hipMemsetAsync(bar,   0, 4096, stream);

    build_whpack2<<<2048, 256, 0, stream>>>(W_lstm_p, W_lstm_h, WhPack2);
    build_wxt    <<<1920, 256, 0, stream>>>(W_lstm_p, W_lstm_h, WxT);

    const int nch = T / CS;
    for (int c = 0; c < nch; ++c){
        dim3 gi(CS*2, 16, 2);
        inproj_mfma<<<gi, 256, 0, stream>>>(premises, hypotheses, WxT,
                                            b_lstm_p, b_lstm_h, XP, c*CS, zrows);
        lstm_chunk<<<256, 256, 0, stream>>>(WhPack2, Apack, XP, Cglob, Hlin,
                                            bar, c*CS, CS, zrows, c*(CS-1));
    }

    dim3 gr(8, 4);
    gemm_tanh_kernel<<<gr,256,0,stream>>>(Hlin,           W_red_p, b_red_p, xbuf, 512, 512, 1024, 0);
    gemm_tanh_kernel<<<gr,256,0,stream>>>(Hlin + 256*512, W_red_h, b_red_h, xbuf, 512, 512, 1024, 512);
    dim3 gm(16, 4);
    gemm_tanh_kernel<<<gm,256,0,stream>>>(xbuf, W1, b1, t1b, 1024, 1024, 1024, 0);
    gemm_tanh_kernel<<<gm,256,0,stream>>>(t1b,  W2, b2, t2b, 1024, 1024, 1024, 0);
    gemm_tanh_kernel<<<gm,256,0,stream>>>(t2b,  W3, b3, t3b, 1024, 1024, 1024, 0);
    out_kernel<<<B/4, 256, 0, stream>>>(t3b, W_out, b_out, out);
}

// Round 7
// 1961.681 us; speedup vs baseline: 3.8546x; 1.6517x over previous
//
#include <hip/hip_runtime.h>
#include <math.h>

#define B 256
#define T 128
#define DD 300
#define H 512
#define FH 2048
#define APK_BUF 524288       // shorts per A-pack buffer

typedef __attribute__((ext_vector_type(8))) short s8v;   // 8 bf16
typedef __attribute__((ext_vector_type(4))) float f4v;   // MFMA acc

__device__ __forceinline__ float sigm(float x){ return 1.0f/(1.0f+expf(-x)); }

__device__ __forceinline__ unsigned short f2bf(float x){
  unsigned u = __float_as_uint(x);
  return (unsigned short)((u + 0x7fffu + ((u>>16)&1u)) >> 16);
}
__device__ __forceinline__ float bf2f(unsigned short b){
  return __uint_as_float(((unsigned)b)<<16);
}

__device__ __forceinline__ f4v MFMA(s8v a, s8v b, f4v c){
  return __builtin_amdgcn_mfma_f32_16x16x32_bf16(a, b, c, 0, 0, 0);
}

// 16B fragment read via two 8B agent-scope relaxed atomic loads: executes at
// the device coherence point (bypasses stale per-XCD L2/L1) -> no acquire
// fence needed. (Empirically validated path: the spin-flag in rounds 4/6
// observed cross-block data with RELAXED agent loads.)
__device__ __forceinline__ s8v ld_a16(const short* p){
  unsigned long long a = __hip_atomic_load((const unsigned long long*)p,
                            __ATOMIC_RELAXED, __HIP_MEMORY_SCOPE_AGENT);
  unsigned long long b = __hip_atomic_load((const unsigned long long*)(p + 4),
                            __ATOMIC_RELAXED, __HIP_MEMORY_SCOPE_AGENT);
  union { unsigned long long q[2]; s8v v; } u;
  u.q[0] = a; u.q[1] = b;
  return u.v;
}

__device__ __forceinline__ void st_a2(short* p, unsigned short v){
  __hip_atomic_store((unsigned short*)p, v,
                     __ATOMIC_RELAXED, __HIP_MEMORY_SCOPE_AGENT);
}

#define GLD16(gp, lp) __builtin_amdgcn_global_load_lds( \
    (__attribute__((address_space(1))) void*)(gp), \
    (__attribute__((address_space(3))) void*)(lp), 16, 0, 0)

// ---------------------------------------------------------------------------
// Recurrent weight pack: [z][nt(32)][sel(2)][kk(16)][g(4)][lane(64)][8] bf16
// col = g*512 + nt*16 + (lane&15); k = kk*32 + (lane>>4)*8 + j (W row DD+k)
// sel0 = hi(W), sel1 = lo(W). Per (z,nt): 128KB contiguous (LDS stage image).
// ---------------------------------------------------------------------------
__global__ __launch_bounds__(256)
void build_whpack2(const float* __restrict__ Wp, const float* __restrict__ Whh,
                   short* __restrict__ out)
{
    int tid = blockIdx.x*256 + threadIdx.x;     // 524288 total
    int lane = tid & 63;
    int rest = tid >> 6;
    int g   = rest & 3;  rest >>= 2;
    int kk  = rest & 15; rest >>= 4;
    int sel = rest & 1;  rest >>= 1;
    int nt  = rest & 31; rest >>= 5;
    int z   = rest;
    const float* W = z ? Whh : Wp;
    int col = g*512 + nt*16 + (lane & 15);
    int kb  = kk*32 + ((lane >> 4) << 3);
    s8v v;
    #pragma unroll
    for (int j = 0; j < 8; ++j){
        float wv = W[(size_t)(DD + kb + j)*FH + col];
        unsigned short hi = f2bf(wv);
        v[j] = (short)(sel ? f2bf(wv - bf2f(hi)) : hi);
    }
    *(s8v*)(out + (size_t)tid*8) = v;
}

// ---------------------------------------------------------------------------
// x-weight B^T split: WxT[z][n(2048)][k'(960)] bf16; k' = seg*320+kr,
// seg {0,1,2} -> {hi, lo, hi} of W[kr][n]; kr>=300 -> 0
// ---------------------------------------------------------------------------
__global__ __launch_bounds__(256)
void build_wxt(const float* __restrict__ Wp, const float* __restrict__ Whh,
               short* __restrict__ out)
{
    int tid = blockIdx.x*256 + threadIdx.x;     // 491520
    int n = tid & 2047;
    int rest = tid >> 11;
    int k8 = rest % 120;
    int z = rest / 120;
    const float* W = z ? Whh : Wp;
    int seg = k8 / 40;
    int krb = (k8 % 40) * 8;
    s8v v;
    #pragma unroll
    for (int j = 0; j < 8; ++j){
        int kr = krb + j;
        unsigned short res = 0;
        if (kr < DD){
            float w = W[(size_t)kr*FH + n];
            unsigned short hi = f2bf(w);
            res = (seg==1) ? f2bf(w - bf2f(hi)) : hi;
        }
        v[j] = (short)res;
    }
    *(s8v*)(out + ((size_t)(z*2048 + n)*120 + k8)*8) = v;
}

// ---------------------------------------------------------------------------
// Input projection GEMM (split-bf16 MFMA), 128x128 tile, BK=64, with FUSED
// fp32->split-bf16 conversion of X on the A side (reg-staged), B via GLD16.
// XPb[z][row(zrows)][2048] = Xsplit(X) @ WxT^T + bias, row = tis*256 + b.
// A k' = seg*320+kr, seg {0,1,2} -> {hi, hi, lo} of X[b][t0+tis][kr].
// ---------------------------------------------------------------------------
__global__ __launch_bounds__(256)
void inproj_mfma(const float* __restrict__ Xp, const float* __restrict__ Xh,
                 const short* __restrict__ WxT,
                 const float* __restrict__ bp, const float* __restrict__ bh,
                 float* __restrict__ XPb, int t0, int zrows)
{
    const int z = blockIdx.z;
    const float* X  = z ? Xh : Xp;
    const short* Bm = WxT + (size_t)z*2048*960;
    const float* bias = z ? bh : bp;
    float* Out = XPb + (size_t)z*zrows*2048;

    const int m0 = blockIdx.x * 128;
    const int n0 = blockIdx.y * 128;
    const int t = threadIdx.x;
    const int lane = t & 63, w = t >> 6;
    const int wm = w & 1, wn = w >> 1;

    __shared__ short Al[128*64];
    __shared__ short Bl[128*64];

    f4v acc[4][4];
    #pragma unroll
    for (int i = 0; i < 4; ++i)
        #pragma unroll
        for (int jj = 0; jj < 4; ++jj) acc[i][jj] = (f4v){0.f,0.f,0.f,0.f};

    const int srow  = t >> 3;        // 0..31
    const int scol8 = (t & 7) * 8;   // k'-element offset within 64-k chunk

    float xreg[4][8];

    auto loadx = [&](int kb){
        const int kp  = kb + scol8;                       // 0..952, mult of 8
        const int seg = (kp >= 640) ? 2 : ((kp >= 320) ? 1 : 0);
        const int kr  = kp - seg*320;                     // 0..312
        #pragma unroll
        for (int r = 0; r < 4; ++r){
            const int rg = m0 + r*32 + srow;
            const float* xr = X + ((size_t)(rg & 255)*T + (t0 + (rg >> 8)))*DD + kr;
            if (kr + 7 < DD){
                float4 a = *(const float4*)xr;
                float4 b = *(const float4*)(xr + 4);
                xreg[r][0]=a.x; xreg[r][1]=a.y; xreg[r][2]=a.z; xreg[r][3]=a.w;
                xreg[r][4]=b.x; xreg[r][5]=b.y; xreg[r][6]=b.z; xreg[r][7]=b.w;
            } else {
                #pragma unroll
                for (int j = 0; j < 8; ++j)
                    xreg[r][j] = (kr + j < DD) ? xr[j] : 0.0f;
            }
        }
    };
    auto pubx = [&](int kb){
        const int kp  = kb + scol8;
        const bool lo = (kp >= 640);
        #pragma unroll
        for (int r = 0; r < 4; ++r){
            s8v o;
            #pragma unroll
            for (int j = 0; j < 8; ++j){
                const float v = xreg[r][j];
                const unsigned short hb = f2bf(v);
                o[j] = (short)(lo ? f2bf(v - bf2f(hb)) : hb);
            }
            *(s8v*)((char*)Al + r*4096 + t*16) = o;
        }
    };

    loadx(0);

    for (int kt = 0; kt < 15; ++kt){
        const int kb = kt*64;
        __syncthreads();                 // LDS free (prev MFMA done)
        pubx(kb);                        // A: convert + ds_write_b128
        #pragma unroll
        for (int r = 0; r < 4; ++r)      // B: async global->LDS
            GLD16(Bm + (size_t)(n0 + r*32 + srow)*960 + kb + scol8,
                  (char*)Bl + r*4096 + t*16);
        __syncthreads();                 // drains vmcnt + lgkm, publishes A,B
        if (kt + 1 < 15) loadx(kb + 64); // prefetch next X regs under MFMA
        #pragma unroll
        for (int kkh = 0; kkh < 2; ++kkh){
            s8v af[4], bf[4];
            #pragma unroll
            for (int mf = 0; mf < 4; ++mf)
                af[mf] = *(const s8v*)((const char*)Al +
                    (wm*64 + mf*16 + (lane&15))*128 + kkh*64 + (lane>>4)*16);
            #pragma unroll
            for (int nf = 0; nf < 4; ++nf)
                bf[nf] = *(const s8v*)((const char*)Bl +
                    (wn*64 + nf*16 + (lane&15))*128 + kkh*64 + (lane>>4)*16);
            #pragma unroll
            for (int mf = 0; mf < 4; ++mf)
                #pragma unroll
                for (int nf = 0; nf < 4; ++nf)
                    acc[mf][nf] = MFMA(af[mf], bf[nf], acc[mf][nf]);
        }
    }

    const int rb = m0 + wm*64, cb = n0 + wn*64;
    #pragma unroll
    for (int nf = 0; nf < 4; ++nf){
        const int c = cb + nf*16 + (lane&15);
        const float bv = bias[c];
        #pragma unroll
        for (int mf = 0; mf < 4; ++mf){
            #pragma unroll
            for (int j = 0; j < 4; ++j){
                const int r = rb + mf*16 + (lane>>4)*4 + j;
                Out[(size_t)r*2048 + c] = acc[mf][nf][j] + bv;
            }
        }
    }
}

// ---------------------------------------------------------------------------
// Persistent LSTM chunk kernel: 256 blocks (1/CU), 256 threads, nsteps steps.
// gid = bx&7 -> all 32 blocks of a group on one XCD (round-robin heuristic;
// correctness does NOT depend on it: h-exchange uses coherence-point atomics).
// Block (z, mt, nt): rows mt*64..+64, hcols nt*16..+16, all 4 gates.
// Weights LDS-resident; C in registers; kk-major K-split across 4 waves;
// b128 cross-wave reduction; XP prefetched one step ahead; NO acquire/release
// fences in the step loop (data via relaxed agent atomics, ordered by the
// vmcnt-drain inside __syncthreads before the flag add).
// ---------------------------------------------------------------------------
__global__ void __launch_bounds__(256, 1)
lstm_chunk(const short* __restrict__ Wpk, short* __restrict__ Apack,
           const float* __restrict__ XP, float* __restrict__ Cglob,
           float* __restrict__ Hlin, unsigned* __restrict__ bar,
           int cstep, int nsteps, int zrows, int bbase)
{
    __shared__ short Wlds[65536];            // 128 KB: [sel][kk][g][lane][8]
    __shared__ f4v zone[4][4][64];           // 16 KB:  [ww][mf][lane]

    const int bx = blockIdx.x;
    const int gid = bx & 7;                  // group (z,mt) -> XCD heuristic
    const int nt  = bx >> 3;                 // 0..31
    const int z   = gid >> 2;
    const int mt  = gid & 3;
    const int t = threadIdx.x;
    const int lane = t & 63;
    const int w = t >> 6;

    // stage weight slice (128 KB linear) into LDS
    const short* wsrc = Wpk + (size_t)(z*32 + nt)*65536;
    #pragma unroll
    for (int it = 0; it < 32; ++it)
        GLD16((const char*)wsrc + it*4096 + t*16, (char*)Wlds + it*4096 + t*16);

    // post-reduction ownership: thread (w,lane) owns rows of mf=w block
    const int col   = nt*16 + (lane & 15);            // global h col
    const int rower = w*16 + ((lane>>4)<<2);          // row within group tile
    const int rbase = mt*64 + rower;                  // +j -> global batch row
    // A-pack write constants (round-trip verified vs fragment reader):
    const int kkw    = nt >> 1;
    const int lanew0 = ((nt & 1)*2 + ((lane & 15) >> 3))*16 + ((lane>>4)<<2);
    const int jw     = lane & 7;

    float cre[4];
    #pragma unroll
    for (int j = 0; j < 4; ++j)
        cre[j] = Cglob[((size_t)z*256 + rbase + j)*512 + col];

    const size_t zmt2 = (size_t)((z*4 + mt)*2);

    // XP for step 0 (overlaps weight staging)
    f4v xpe[4];
    {
        const float* XPz = XP + ((size_t)z*zrows + mt*64)*2048;
        #pragma unroll
        for (int g = 0; g < 4; ++g)
            #pragma unroll
            for (int j = 0; j < 4; ++j)
                xpe[g][j] = XPz[(size_t)(rower + j)*2048 + g*512 + col];
    }

    __syncthreads();                         // weights staged (drains vmcnt)

    for (int s = 0; s < nsteps; ++s){
        const int gstep = cstep + s;
        const short* rdp = Apack + ((gstep & 1) ? APK_BUF : 0);
        short*       wrp = Apack + ((gstep & 1) ? 0 : APK_BUF);

        // ---- MFMA phase: kk-major; wave w owns kk = 4w..4w+3 ----
        // All 32 A fragments (hi+lo) issued upfront: one L3 latency exposure.
        const short* ah = rdp + zmt2*32768 + (size_t)(w*4)*2048 + lane*8;
        s8v ahi[4][4], alo[4][4];
        #pragma unroll
        for (int i = 0; i < 4; ++i)
            #pragma unroll
            for (int mf = 0; mf < 4; ++mf){
                ahi[i][mf] = ld_a16(ah + i*2048 + mf*512);
                alo[i][mf] = ld_a16(ah + 32768 + i*2048 + mf*512);
            }

        f4v acc[4][4];
        #pragma unroll
        for (int mf = 0; mf < 4; ++mf)
            #pragma unroll
            for (int g = 0; g < 4; ++g) acc[mf][g] = (f4v){0.f,0.f,0.f,0.f};

        #pragma unroll
        for (int i = 0; i < 4; ++i){
            const short* wb = Wlds + (w*4 + i)*2048 + lane*8;
            s8v whi[4], wlo[4];
            #pragma unroll
            for (int g = 0; g < 4; ++g){
                whi[g] = *(const s8v*)(wb + g*512);
                wlo[g] = *(const s8v*)(wb + 32768 + g*512);
            }
            // three split-product pairings per kk, same accumulators
            #pragma unroll
            for (int mf = 0; mf < 4; ++mf)
                #pragma unroll
                for (int g = 0; g < 4; ++g){
                    acc[mf][g] = MFMA(ahi[i][mf], whi[g], acc[mf][g]);
                    acc[mf][g] = MFMA(ahi[i][mf], wlo[g], acc[mf][g]);
                    acc[mf][g] = MFMA(alo[i][mf], whi[g], acc[mf][g]);
                }
        }

        // ---- cross-wave reduction: 4 rounds, all-b128 ----
        f4v gv[4];
        #pragma unroll
        for (int g = 0; g < 4; ++g){
            __syncthreads();
            #pragma unroll
            for (int mf = 0; mf < 4; ++mf)
                zone[w][mf][lane] = acc[mf][g];
            __syncthreads();
            gv[g] = zone[0][w][lane] + zone[1][w][lane]
                  + zone[2][w][lane] + zone[3][w][lane];
        }

        // ---- prefetch next-step XP into registers (fence-immune) ----
        const bool more = (s + 1 < nsteps);
        f4v xnw[4];
        if (more){
            const float* XPn = XP + ((size_t)z*zrows + (size_t)(s+1)*256 + mt*64)*2048;
            #pragma unroll
            for (int g = 0; g < 4; ++g)
                #pragma unroll
                for (int j = 0; j < 4; ++j)
                    xnw[g][j] = XPn[(size_t)(rower + j)*2048 + g*512 + col];
        }

        // ---- gates + state update + A-pack write (coherence-point stores) --
        short* d0 = wrp + zmt2*32768 + kkw*2048 + w*512 + jw;
        #pragma unroll
        for (int j = 0; j < 4; ++j){
            const float zi = gv[0][j] + xpe[0][j];
            const float zj = gv[1][j] + xpe[1][j];
            const float zf = gv[2][j] + xpe[2][j];
            const float zo = gv[3][j] + xpe[3][j];
            const float cn = cre[j]*sigm(zf + 1.0f) + sigm(zi)*tanhf(zj);
            const float hn = tanhf(cn)*sigm(zo);
            cre[j] = cn;
            const unsigned short hb = f2bf(hn);
            const unsigned short lb = f2bf(hn - bf2f(hb));
            st_a2(d0 + (lanew0 + j)*8,         hb);
            st_a2(d0 + 32768 + (lanew0 + j)*8, lb);
            if (gstep == T-1)
                Hlin[((size_t)z*256 + rbase + j)*512 + col] = hn;
        }

        // ---- group flag barrier, fence-free ----
        // __syncthreads drains vmcnt: all atomic stores completed at the
        // coherence point BEFORE t0 increments the flag. Readers' data loads
        // are atomic (coherence-point) -> no invalidate needed.
        if (more){
            __syncthreads();
            if (t == 0){
                __hip_atomic_fetch_add(&bar[gid*16], 1u, __ATOMIC_RELAXED,
                                       __HIP_MEMORY_SCOPE_AGENT);
                const unsigned tgt = 32u*(unsigned)(bbase + s + 1);
                while (__hip_atomic_load(&bar[gid*16], __ATOMIC_RELAXED,
                                         __HIP_MEMORY_SCOPE_AGENT) < tgt)
                    __builtin_amdgcn_s_sleep(2);
            }
            __syncthreads();
            #pragma unroll
            for (int g = 0; g < 4; ++g) xpe[g] = xnw[g];
        }
    }

    #pragma unroll
    for (int j = 0; j < 4; ++j)
        Cglob[((size_t)z*256 + rbase + j)*512 + col] = cre[j];
}

// ---------------------------------------------------------------------------
// fp32 tail
// ---------------------------------------------------------------------------
__global__ __launch_bounds__(256)
void gemm_tanh_kernel(const float* __restrict__ A, const float* __restrict__ W,
                      const float* __restrict__ bias, float* __restrict__ Cout,
                      int K, int N, int ldc, int coloff)
{
    const int n0 = blockIdx.x * 64;
    const int m0 = blockIdx.y * 64;
    const int t  = threadIdx.x;
    const int rc = t >> 4, cc = t & 15;

    __shared__ float As[16][68];
    __shared__ float Bs[16][64];

    float acc[4][4] = {};
    float areg[4], breg[4];

    const int ar = t >> 2;
    const int kq = (t & 3) * 4;
    const int kb = t >> 4;
    const int nb = (t & 15) * 4;

    {
        const float4 av = *(const float4*)(A + (size_t)(m0 + ar) * K + kq);
        areg[0]=av.x; areg[1]=av.y; areg[2]=av.z; areg[3]=av.w;
        const float4 bv = *(const float4*)(W + (size_t)kb * N + n0 + nb);
        breg[0]=bv.x; breg[1]=bv.y; breg[2]=bv.z; breg[3]=bv.w;
    }

    const int KT = K / 16;
    for (int kt = 0; kt < KT; ++kt){
        __syncthreads();
        As[kq+0][ar] = areg[0];
        As[kq+1][ar] = areg[1];
        As[kq+2][ar] = areg[2];
        As[kq+3][ar] = areg[3];
        *(float4*)&Bs[kb][nb] = make_float4(breg[0], breg[1], breg[2], breg[3]);
        __syncthreads();

        if (kt + 1 < KT){
            const int k0 = (kt + 1) * 16;
            const float4 av = *(const float4*)(A + (size_t)(m0 + ar) * K + k0 + kq);
            areg[0]=av.x; areg[1]=av.y; areg[2]=av.z; areg[3]=av.w;
            const float4 bv = *(const float4*)(W + (size_t)(k0 + kb) * N + n0 + nb);
            breg[0]=bv.x; breg[1]=bv.y; breg[2]=bv.z; breg[3]=bv.w;
        }

        #pragma unroll
        for (int k = 0; k < 16; ++k){
            const float4 a = *(const float4*)&As[k][4*rc];
            const float4 b = *(const float4*)&Bs[k][4*cc];
            acc[0][0] += a.x*b.x; acc[0][1] += a.x*b.y; acc[0][2] += a.x*b.z; acc[0][3] += a.x*b.w;
            acc[1][0] += a.y*b.x; acc[1][1] += a.y*b.y; acc[1][2] += a.y*b.z; acc[1][3] += a.y*b.w;
            acc[2][0] += a.z*b.x; acc[2][1] += a.z*b.y; acc[2][2] += a.z*b.z; acc[2][3] += a.z*b.w;
            acc[3][0] += a.w*b.x; acc[3][1] += a.w*b.y; acc[3][2] += a.w*b.z; acc[3][3] += a.w*b.w;
        }
    }

    const float4 bv = *(const float4*)(bias + n0 + 4*cc);
    #pragma unroll
    for (int ri = 0; ri < 4; ++ri){
        const int rg = m0 + 4*rc + ri;
        float4 res;
        res.x = tanhf(acc[ri][0] + bv.x);
        res.y = tanhf(acc[ri][1] + bv.y);
        res.z = tanhf(acc[ri][2] + bv.z);
        res.w = tanhf(acc[ri][3] + bv.w);
        *(float4*)&Cout[(size_t)rg * ldc + coloff + n0 + 4*cc] = res;
    }
}

__global__ __launch_bounds__(256)
void out_kernel(const float* __restrict__ A, const float* __restrict__ Wo,
                const float* __restrict__ bo, float* __restrict__ out)
{
    const int wave = threadIdx.x >> 6;
    const int lane = threadIdx.x & 63;
    const int r = blockIdx.x * 4 + wave;

    float a0 = 0.f, a1 = 0.f, a2 = 0.f;
    for (int k = lane; k < 1024; k += 64){
        const float a = A[(size_t)r * 1024 + k];
        a0 += a * Wo[k*3 + 0];
        a1 += a * Wo[k*3 + 1];
        a2 += a * Wo[k*3 + 2];
    }
    #pragma unroll
    for (int off = 32; off > 0; off >>= 1){
        a0 += __shfl_down(a0, off);
        a1 += __shfl_down(a1, off);
        a2 += __shfl_down(a2, off);
    }
    if (lane == 0){
        out[r*3 + 0] = a0 + bo[0];
        out[r*3 + 1] = a1 + bo[1];
        out[r*3 + 2] = a2 + bo[2];
    }
}

// ---------------------------------------------------------------------------
extern "C" void kernel_launch(void* const* d_in, const int* in_sizes, int n_in,
                              void* d_out, int out_size, void* d_ws, size_t ws_size,
                              hipStream_t stream)
{
    const float* premises   = (const float*)d_in[0];
    const float* hypotheses = (const float*)d_in[1];
    const float* W_lstm_p   = (const float*)d_in[2];
    const float* b_lstm_p   = (const float*)d_in[3];
    const float* W_lstm_h   = (const float*)d_in[4];
    const float* b_lstm_h   = (const float*)d_in[5];
    const float* W_red_p    = (const float*)d_in[6];
    const float* b_red_p    = (const float*)d_in[7];
    const float* W_red_h    = (const float*)d_in[8];
    const float* b_red_h    = (const float*)d_in[9];
    const float* W1 = (const float*)d_in[10];  const float* b1 = (const float*)d_in[11];
    const float* W2 = (const float*)d_in[12];  const float* b2 = (const float*)d_in[13];
    const float* W3 = (const float*)d_in[14];  const float* b3 = (const float*)d_in[15];
    const float* W_out = (const float*)d_in[16]; const float* b_out = (const float*)d_in[17];
    float* out = (float*)d_out;

    // need(CS) = fixed ~24.7 MB + XP (CS*4.20 MB)
    const int CS = (ws_size >= 92000000ull) ? 16 : 8;
    const int zrows = CS * 256;

    char* wsb = (char*)d_ws;
    size_t off = 0;
    auto alloc = [&](size_t bytes)->void*{
        void* p = wsb + off; off += (bytes + 255) & ~(size_t)255; return p;
    };
    short*    WhPack2 = (short*)alloc(4194304ull*2);            //  8.39 MB
    short*    WxT     = (short*)alloc(2ull*2048*960*2);         //  7.86 MB
    short*    Apack   = (short*)alloc(2ull*APK_BUF*2);          //  2.10 MB
    float*    Cglob   = (float*)alloc(2ull*256*512*4);          //  1.05 MB
    float*    Hlin    = (float*)alloc(2ull*256*512*4);          //  1.05 MB
    float*    XP      = (float*)alloc(2ull*zrows*2048*4);       // 33.5/67.1 MB
    float*    xbuf    = (float*)alloc(256ull*1024*4);
    float*    t1b     = (float*)alloc(256ull*1024*4);
    float*    t2b     = (float*)alloc(256ull*1024*4);
    float*    t3b     = (float*)alloc(256ull*1024*4);
    unsigned* bar     = (unsigned*)alloc(4096);

    hipMemsetAsync(Apack, 0, 2ull*APK_BUF*2, stream);
    hipMemsetAsync(Cglob, 0, 2ull*256*512*4, stream);
    hipMemsetAsync(bar,   0, 4096, stream);

    build_whpack2<<<2048, 256, 0, stream>>>(W_lstm_p, W_lstm_h, WhPack2);
    build_wxt    <<<1920, 256, 0, stream>>>(W_lstm_p, W_lstm_h, WxT);

    const int nch = T / CS;
    for (int c = 0; c < nch; ++c){
        dim3 gi(CS*2, 16, 2);
        inproj_mfma<<<gi, 256, 0, stream>>>(premises, hypotheses, WxT,
                                            b_lstm_p, b_lstm_h, XP, c*CS, zrows);
        lstm_chunk<<<256, 256, 0, stream>>>(WhPack2, Apack, XP, Cglob, Hlin,
                                            bar, c*CS, CS, zrows, c*(CS-1));
    }

    dim3 gr(8, 4);
    gemm_tanh_kernel<<<gr,256,0,stream>>>(Hlin,           W_red_p, b_red_p, xbuf, 512, 512, 1024, 0);
    gemm_tanh_kernel<<<gr,256,0,stream>>>(Hlin + 256*512, W_red_h, b_red_h, xbuf, 512, 512, 1024, 512);
    dim3 gm(16, 4);
    gemm_tanh_kernel<<<gm,256,0,stream>>>(xbuf, W1, b1, t1b, 1024, 1024, 1024, 0);
    gemm_tanh_kernel<<<gm,256,0,stream>>>(t1b,  W2, b2, t2b, 1024, 1024, 1024, 0);
    gemm_tanh_kernel<<<gm,256,0,stream>>>(t2b,  W3, b3, t3b, 1024, 1024, 1024, 0);
    out_kernel<<<B/4, 256, 0, stream>>>(t3b, W_out, b_out, out);
}